// Round 10
// baseline (442.200 us; speedup 1.0000x reference)
//
#include <hip/hip_runtime.h>
#include <hip/hip_bf16.h>

// GIN net, round 10: gather fused into the MLP kernel (CSR edge loop produces
// zr[i][j] in registers, Phase A transposes to LDS as before). Deletes the
// aggr buffer round-trip (25.6MB f32 w+r per layer) and 3 kernel launches;
// gather's memory phase overlaps other blocks' compute. bf16 features (r9),
// deterministic bucket-sort CSR build (r8), segmented pool, BN folds as before.

#define HD 64
#define NBLK 256     // edge-chunk blocks
#define BSH 9        // bucket = 512 nodes; requires N <= 131072 (src fits 17 bits)

typedef unsigned short u16;

__device__ __forceinline__ float bf2f(u16 u) {
    return __uint_as_float(((unsigned int)u) << 16);
}
__device__ __forceinline__ u16 f2bf(float f) {       // round-to-nearest-even
    unsigned int u = __float_as_uint(f);
    unsigned int r = 0x7FFFu + ((u >> 16) & 1u);
    return (u16)((u + r) >> 16);
}

// ================= CSR build: deterministic two-pass bucket sort (r8) ============
__global__ void hist_kernel(const int* __restrict__ ei, int* __restrict__ ghist, int E, int C) {
    __shared__ int lh[256];
    int b = blockIdx.x, tid = threadIdx.x;
    lh[tid] = 0;
    __syncthreads();
    int beg = b * C, end = min(beg + C, E);
    for (int i = beg + tid; i < end; i += 256) atomicAdd(&lh[ei[E + i] >> BSH], 1);
    __syncthreads();
    ghist[b * 256 + tid] = lh[tid];
}

__global__ void colscan_kernel(int* __restrict__ ghist, int* __restrict__ total) {
    __shared__ int s[256];
    int k = blockIdx.x, b = threadIdx.x;
    int v = ghist[b * 256 + k];
    s[b] = v;
    __syncthreads();
    for (int off = 1; off < 256; off <<= 1) {
        int u = (b >= off) ? s[b - off] : 0;
        __syncthreads();
        s[b] += u;
        __syncthreads();
    }
    ghist[b * 256 + k] = s[b] - v;
    if (b == 255) total[k] = s[255];
}

__global__ void base_kernel(const int* __restrict__ total, int* __restrict__ bbase, int NBUCK) {
    __shared__ int s[256];
    int t = threadIdx.x;
    int v = (t < NBUCK) ? total[t] : 0;
    s[t] = v;
    __syncthreads();
    for (int off = 1; off < 256; off <<= 1) {
        int u = (t >= off) ? s[t - off] : 0;
        __syncthreads();
        s[t] += u;
        __syncthreads();
    }
    if (t == 0) bbase[0] = 0;
    bbase[t + 1] = s[t];
}

__global__ void scatter_kernel(const int* __restrict__ ei, const int* __restrict__ ghist,
                               const int* __restrict__ bbase, int* __restrict__ bpack,
                               int E, int C) {
    __shared__ int lcur[256];
    int b = blockIdx.x, tid = threadIdx.x;
    lcur[tid] = bbase[tid] + ghist[b * 256 + tid];
    __syncthreads();
    int beg = b * C, end = min(beg + C, E);
    for (int i = beg + tid; i < end; i += 256) {
        int src = ei[i], dst = ei[E + i];
        int pos = atomicAdd(&lcur[dst >> BSH], 1);
        bpack[pos] = src | ((dst & 511) << 17);
    }
}

__global__ void csrbuild_kernel(const int* __restrict__ bpack, const int* __restrict__ bbase,
                                int* __restrict__ row_start, int* __restrict__ csr, int N) {
    __shared__ int h[512], s[512], lc[512];
    int k = blockIdx.x, tid = threadIdx.x;
    int beg = bbase[k], end = bbase[k + 1];
    h[tid] = 0; h[tid + 256] = 0;
    __syncthreads();
    for (int i = beg + tid; i < end; i += 256) atomicAdd(&h[(bpack[i] >> 17) & 511], 1);
    __syncthreads();
    s[tid] = h[tid]; s[tid + 256] = h[tid + 256];
    __syncthreads();
    for (int off = 1; off < 512; off <<= 1) {
        int v0 = (tid >= off) ? s[tid - off] : 0;
        int t1 = tid + 256;
        int v1 = (t1 >= off) ? s[t1 - off] : 0;
        __syncthreads();
        s[tid] += v0; s[t1] += v1;
        __syncthreads();
    }
    int e0 = s[tid] - h[tid], e1 = s[tid + 256] - h[tid + 256];
    lc[tid] = e0; lc[tid + 256] = e1;
    int n0 = (k << BSH) + tid, n1 = (k << BSH) + tid + 256;
    if (n0 < N) row_start[n0] = beg + e0;
    if (n1 < N) row_start[n1] = beg + e1;
    if (k == gridDim.x - 1 && tid == 0) row_start[N] = end;
    __syncthreads();
    for (int i = beg + tid; i < end; i += 256) {
        int v = bpack[i];
        int pos = beg + atomicAdd(&lc[(v >> 17) & 511], 1);
        csr[pos] = v & 0x1FFFF;
    }
}

// ======== fused gather + MLP ========
// thread (tc=tid&15, tn=tid>>4). DIN=64: gathers 4 nodes (tn*4+i) x 4ch (tc*4)
// via 16-lane shuffle-broadcast edge loop (bf16 rows). DIN=16: 1 node
// (tn*4 + (tc>>2)) x 4ch ((tc&3)*4), 4-lane groups, f32 x.
// AFF: prev-layer BN folded (Wa_eff = diag(a)Wa, bias += (1+eps+deg)*(c@Wa)).
template <int DIN, bool AFF>
__launch_bounds__(256)
__global__ void fused_mlp_kernel(const void* __restrict__ xin_,
                                 const int* __restrict__ rs, const int* __restrict__ csr,
                                 const float* __restrict__ Wa, const float* __restrict__ ba,
                                 const float* __restrict__ Wb, const float* __restrict__ bb,
                                 const float* __restrict__ epsp,
                                 const float* __restrict__ statsPrev,
                                 const float* __restrict__ gPrev, const float* __restrict__ bePrev,
                                 u16* __restrict__ hout, float* __restrict__ stats, int N) {
    __shared__ float Wa_s[DIN * 64];
    __shared__ float Wb_s[64 * 64];
    __shared__ float zts[64 * 68];
    __shared__ float statS[128];
    __shared__ float degS[64];
    __shared__ float aS[64], cS[64], uS[64];

    const int tid = threadIdx.x;
    const int tc = tid & 15;
    const int tn = tid >> 4;
    const float* xinF = (const float*)xin_;
    const u16*   xinB = (const u16*)xin_;

    if (AFF) {
        if (tid < 64) {
            float invN = 1.0f / (float)N;
            float mu = statsPrev[tid] * invN;
            float var = statsPrev[64 + tid] * invN - mu * mu;
            float inv = rsqrtf(var + 1e-5f);
            float a = gPrev[tid] * inv;
            aS[tid] = a;
            cS[tid] = bePrev[tid] - mu * a;
        }
        __syncthreads();
        for (int i = tid; i < DIN * 64; i += 256) Wa_s[i] = aS[i >> 6] * Wa[i];
        if (tid < 64) {
            float s = 0.0f;
            for (int k = 0; k < 64; k++) s = fmaf(cS[k], Wa[k * 64 + tid], s);
            uS[tid] = s;
        }
    } else {
        for (int i = tid; i < DIN * 64; i += 256) Wa_s[i] = Wa[i];
    }
    for (int i = tid; i < 64 * 64; i += 256) Wb_s[i] = Wb[i];
    if (tid < 128) statS[tid] = 0.0f;
    const float e1 = 1.0f + epsp[0];
    __syncthreads();

    float4 t4;
    t4 = *(const float4*)&ba[tc * 4];
    const float bav[4] = {t4.x, t4.y, t4.z, t4.w};
    t4 = *(const float4*)&bb[tc * 4];
    const float bbv[4] = {t4.x, t4.y, t4.z, t4.w};
    float uv[4] = {0, 0, 0, 0};
    if (AFF) { uv[0] = uS[tc * 4]; uv[1] = uS[tc * 4 + 1]; uv[2] = uS[tc * 4 + 2]; uv[3] = uS[tc * 4 + 3]; }

    float sv[4] = {0, 0, 0, 0}, qv[4] = {0, 0, 0, 0};

    const int ITER = 2;
    int blockBase = blockIdx.x * (64 * ITER);
    for (int it = 0; it < ITER; ++it) {
        int gbase = blockBase + it * 64;
        // ---- Phase G: fused gather -> zr registers ----
        float zr[4][4];
        if (DIN == 64) {
#pragma unroll
            for (int i = 0; i < 4; ++i) {
                int node = gbase + tn * 4 + i;
                float a0x = 0, a0y = 0, a0z = 0, a0w = 0;
                float a1x = 0, a1y = 0, a1z = 0, a1w = 0;
                float a2x = 0, a2y = 0, a2z = 0, a2w = 0;
                float a3x = 0, a3y = 0, a3z = 0, a3w = 0;
                if (node < N) {
                    int beg = rs[node], end = rs[node + 1];
                    const u16* xb = xinB + (size_t)tc * 4;
                    for (int base = beg; base < end; base += 16) {
                        int cnt = end - base; if (cnt > 16) cnt = 16;
                        int e = (tc < cnt) ? csr[base + tc] : 0;
                        int j = 0;
                        for (; j + 4 <= cnt; j += 4) {
                            int s0 = __shfl(e, j + 0, 16);
                            int s1 = __shfl(e, j + 1, 16);
                            int s2 = __shfl(e, j + 2, 16);
                            int s3 = __shfl(e, j + 3, 16);
                            ushort4 u0 = *(const ushort4*)(xb + (size_t)s0 * 64);
                            ushort4 u1 = *(const ushort4*)(xb + (size_t)s1 * 64);
                            ushort4 u2 = *(const ushort4*)(xb + (size_t)s2 * 64);
                            ushort4 u3 = *(const ushort4*)(xb + (size_t)s3 * 64);
                            a0x += bf2f(u0.x); a0y += bf2f(u0.y); a0z += bf2f(u0.z); a0w += bf2f(u0.w);
                            a1x += bf2f(u1.x); a1y += bf2f(u1.y); a1z += bf2f(u1.z); a1w += bf2f(u1.w);
                            a2x += bf2f(u2.x); a2y += bf2f(u2.y); a2z += bf2f(u2.z); a2w += bf2f(u2.w);
                            a3x += bf2f(u3.x); a3y += bf2f(u3.y); a3z += bf2f(u3.z); a3w += bf2f(u3.w);
                        }
                        for (; j < cnt; j++) {
                            int s = __shfl(e, j, 16);
                            ushort4 u = *(const ushort4*)(xb + (size_t)s * 64);
                            a0x += bf2f(u.x); a0y += bf2f(u.y); a0z += bf2f(u.z); a0w += bf2f(u.w);
                        }
                    }
                    ushort4 xs = *(const ushort4*)&xinB[(size_t)node * 64 + tc * 4];
                    zr[i][0] = fmaf(e1, bf2f(xs.x), (a0x + a1x) + (a2x + a3x));
                    zr[i][1] = fmaf(e1, bf2f(xs.y), (a0y + a1y) + (a2y + a3y));
                    zr[i][2] = fmaf(e1, bf2f(xs.z), (a0z + a1z) + (a2z + a3z));
                    zr[i][3] = fmaf(e1, bf2f(xs.w), (a0w + a1w) + (a2w + a3w));
                } else {
                    zr[i][0] = zr[i][1] = zr[i][2] = zr[i][3] = 0.0f;
                }
            }
        } else {
            int node = gbase + tn * 4 + (tc >> 2);
            int cq = (tc & 3) * 4;
            float a0x = 0, a0y = 0, a0z = 0, a0w = 0;
            float a1x = 0, a1y = 0, a1z = 0, a1w = 0;
            float a2x = 0, a2y = 0, a2z = 0, a2w = 0;
            float a3x = 0, a3y = 0, a3z = 0, a3w = 0;
            if (node < N) {
                int beg = rs[node], end = rs[node + 1];
                const float* xb = xinF + (size_t)cq;
                int l4 = tc & 3;
                for (int base = beg; base < end; base += 4) {
                    int cnt = end - base; if (cnt > 4) cnt = 4;
                    int e = (l4 < cnt) ? csr[base + l4] : 0;
                    if (cnt == 4) {
                        int s0 = __shfl(e, 0, 4);
                        int s1 = __shfl(e, 1, 4);
                        int s2 = __shfl(e, 2, 4);
                        int s3 = __shfl(e, 3, 4);
                        float4 v0 = *(const float4*)(xb + (size_t)s0 * 16);
                        float4 v1 = *(const float4*)(xb + (size_t)s1 * 16);
                        float4 v2 = *(const float4*)(xb + (size_t)s2 * 16);
                        float4 v3 = *(const float4*)(xb + (size_t)s3 * 16);
                        a0x += v0.x; a0y += v0.y; a0z += v0.z; a0w += v0.w;
                        a1x += v1.x; a1y += v1.y; a1z += v1.z; a1w += v1.w;
                        a2x += v2.x; a2y += v2.y; a2z += v2.z; a2w += v2.w;
                        a3x += v3.x; a3y += v3.y; a3z += v3.z; a3w += v3.w;
                    } else {
                        for (int j = 0; j < cnt; j++) {
                            int s = __shfl(e, j, 4);
                            float4 v = *(const float4*)(xb + (size_t)s * 16);
                            a0x += v.x; a0y += v.y; a0z += v.z; a0w += v.w;
                        }
                    }
                }
                float4 xs = *(const float4*)&xinF[(size_t)node * 16 + cq];
                zr[0][0] = fmaf(e1, xs.x, (a0x + a1x) + (a2x + a3x));
                zr[0][1] = fmaf(e1, xs.y, (a0y + a1y) + (a2y + a3y));
                zr[0][2] = fmaf(e1, xs.z, (a0z + a1z) + (a2z + a3z));
                zr[0][3] = fmaf(e1, xs.w, (a0w + a1w) + (a2w + a3w));
            } else {
                zr[0][0] = zr[0][1] = zr[0][2] = zr[0][3] = 0.0f;
            }
        }
        float dg[4];
        if (AFF && tid < 64) {
            int node = gbase + tid;
            degS[tid] = (node < N) ? (float)(rs[node + 1] - rs[node]) : 0.0f;
        }
        __syncthreads();                       // bar0: prev iter's zts reads done
        if (DIN == 64) {
#pragma unroll
            for (int j = 0; j < 4; ++j) {
                float4 w = {zr[0][j], zr[1][j], zr[2][j], zr[3][j]};
                *(float4*)&zts[(tc * 4 + j) * 68 + tn * 4] = w;
            }
        } else {
#pragma unroll
            for (int j = 0; j < 4; ++j)
                zts[((tc & 3) * 4 + j) * 68 + tn * 4 + (tc >> 2)] = zr[0][j];
        }
        __syncthreads();                       // bar1: z tile ready
        if (AFF) {
#pragma unroll
            for (int i = 0; i < 4; ++i) dg[i] = e1 + degS[tn * 4 + i];
        }
        float ac[4][4];
#pragma unroll
        for (int i = 0; i < 4; ++i)
#pragma unroll
            for (int j = 0; j < 4; ++j)
                ac[i][j] = AFF ? fmaf(dg[i], uv[j], bav[j]) : bav[j];
#pragma unroll 8
        for (int k = 0; k < DIN; ++k) {
            float4 zv = *(const float4*)&zts[k * 68 + tn * 4];
            float4 wv = *(const float4*)&Wa_s[k * 64 + tc * 4];
            const float zf[4] = {zv.x, zv.y, zv.z, zv.w};
            const float wf[4] = {wv.x, wv.y, wv.z, wv.w};
#pragma unroll
            for (int i = 0; i < 4; ++i)
#pragma unroll
                for (int j = 0; j < 4; ++j)
                    ac[i][j] = fmaf(zf[i], wf[j], ac[i][j]);
        }
#pragma unroll
        for (int i = 0; i < 4; ++i)
#pragma unroll
            for (int j = 0; j < 4; ++j)
                ac[i][j] = fmaxf(ac[i][j], 0.0f);
        __syncthreads();                       // bar2: z tile consumed
#pragma unroll
        for (int j = 0; j < 4; ++j) {
            float4 w = {ac[0][j], ac[1][j], ac[2][j], ac[3][j]};
            *(float4*)&zts[(tc * 4 + j) * 68 + tn * 4] = w;
        }
        __syncthreads();                       // bar3: t tile ready
        float hc[4][4];
#pragma unroll
        for (int i = 0; i < 4; ++i)
#pragma unroll
            for (int j = 0; j < 4; ++j)
                hc[i][j] = bbv[j];
#pragma unroll 8
        for (int k = 0; k < 64; ++k) {
            float4 tv = *(const float4*)&zts[k * 68 + tn * 4];
            float4 wv = *(const float4*)&Wb_s[k * 64 + tc * 4];
            const float tf[4] = {tv.x, tv.y, tv.z, tv.w};
            const float wf[4] = {wv.x, wv.y, wv.z, wv.w};
#pragma unroll
            for (int i = 0; i < 4; ++i)
#pragma unroll
                for (int j = 0; j < 4; ++j)
                    hc[i][j] = fmaf(tf[i], wf[j], hc[i][j]);
        }
#pragma unroll
        for (int i = 0; i < 4; ++i) {
            int node = gbase + tn * 4 + i;
            if (node < N) {
                float o0 = fmaxf(hc[i][0], 0.0f), o1 = fmaxf(hc[i][1], 0.0f);
                float o2 = fmaxf(hc[i][2], 0.0f), o3 = fmaxf(hc[i][3], 0.0f);
                ushort4 ob = {f2bf(o0), f2bf(o1), f2bf(o2), f2bf(o3)};
                *(ushort4*)&hout[(size_t)node * 64 + tc * 4] = ob;
                sv[0] += o0; sv[1] += o1; sv[2] += o2; sv[3] += o3;
                qv[0] += o0 * o0; qv[1] += o1 * o1; qv[2] += o2 * o2; qv[3] += o3 * o3;
            }
        }
    }
#pragma unroll
    for (int off = 16; off < 64; off <<= 1) {
#pragma unroll
        for (int j = 0; j < 4; ++j) {
            sv[j] += __shfl_xor(sv[j], off);
            qv[j] += __shfl_xor(qv[j], off);
        }
    }
    if ((tid & 63) < 16) {
#pragma unroll
        for (int j = 0; j < 4; ++j) {
            atomicAdd(&statS[tc * 4 + j], sv[j]);
            atomicAdd(&statS[64 + tc * 4 + j], qv[j]);
        }
    }
    __syncthreads();
    if (tid < 128) unsafeAtomicAdd(&stats[tid], statS[tid]);
}

// ================= segmented pool (batch sorted), bf16 input =================
__global__ void pool_seg_kernel(const u16* __restrict__ h, const int* __restrict__ batch,
                                float* __restrict__ pool, float* __restrict__ cnt, int N) {
    int lane = threadIdx.x & 63;
    int wave = (blockIdx.x * blockDim.x + threadIdx.x) >> 6;
    int base = wave * 16;
    if (base >= N) return;
    int end = base + 16; if (end > N) end = N;
    int cur = batch[base];
    float acc = 0.0f;
    int run = 0;
    for (int n = base; n < end; n++) {
        int gid = batch[n];
        if (gid != cur) {
            unsafeAtomicAdd(&pool[(size_t)cur * 64 + lane], acc);
            if (lane == 0) unsafeAtomicAdd(&cnt[cur], (float)run);
            acc = 0.0f; run = 0; cur = gid;
        }
        acc += bf2f(h[(size_t)n * 64 + lane]);
        run++;
    }
    unsafeAtomicAdd(&pool[(size_t)cur * 64 + lane], acc);
    if (lane == 0) unsafeAtomicAdd(&cnt[cur], (float)run);
}

// ================= readout (applies BN3 affine to pooled mean) =================
__global__ void readout_kernel(const float* __restrict__ pool, const float* __restrict__ cnt,
                               const float* __restrict__ stats, const float* __restrict__ g3,
                               const float* __restrict__ be3,
                               const float* __restrict__ Wf1, const float* __restrict__ bf1,
                               const float* __restrict__ Wf2, const float* __restrict__ bf2,
                               float* __restrict__ out, int N) {
    int gb = blockIdx.x;
    int t = threadIdx.x;  // 64 threads
    float invN = 1.0f / (float)N;
    float mu = stats[t] * invN;
    float var = stats[64 + t] * invN - mu * mu;
    float inv = rsqrtf(var + 1e-5f);
    float a = g3[t] * inv;
    float c = be3[t] - mu * a;
    float cn = cnt[gb];
    float p = (cn > 0.0f) ? (a * (pool[(size_t)gb * 64 + t] / cn) + c) : 0.0f;
    float o = 0.0f;
#pragma unroll
    for (int j = 0; j < 10; j++) {
        float part = p * Wf1[t * 10 + j];
#pragma unroll
        for (int off = 32; off > 0; off >>= 1) part += __shfl_down(part, off);
        float z = fmaxf(part + bf1[j], 0.0f);   // valid on lane 0 only
        o = fmaf(z, Wf2[j], o);
    }
    if (t == 0) out[gb] = o + bf2[0];
}

extern "C" void kernel_launch(void* const* d_in, const int* in_sizes, int n_in,
                              void* d_out, int out_size, void* d_ws, size_t ws_size,
                              hipStream_t stream) {
    const float* x      = (const float*)d_in[0];
    const int*   ei     = (const int*)d_in[1];
    const int*   batch  = (const int*)d_in[2];
    const float* W1a = (const float*)d_in[3];  const float* b1a = (const float*)d_in[4];
    const float* W1b = (const float*)d_in[5];  const float* b1b = (const float*)d_in[6];
    const float* e1  = (const float*)d_in[7];  const float* g1  = (const float*)d_in[8];
    const float* be1 = (const float*)d_in[9];
    const float* W2a = (const float*)d_in[10]; const float* b2a = (const float*)d_in[11];
    const float* W2b = (const float*)d_in[12]; const float* b2b = (const float*)d_in[13];
    const float* e2  = (const float*)d_in[14]; const float* g2  = (const float*)d_in[15];
    const float* be2 = (const float*)d_in[16];
    const float* W3a = (const float*)d_in[17]; const float* b3a = (const float*)d_in[18];
    const float* W3b = (const float*)d_in[19]; const float* b3b = (const float*)d_in[20];
    const float* e3  = (const float*)d_in[21]; const float* g3  = (const float*)d_in[22];
    const float* be3 = (const float*)d_in[23];
    const float* Wf1 = (const float*)d_in[24]; const float* bf1 = (const float*)d_in[25];
    const float* Wf2 = (const float*)d_in[26]; const float* bf2 = (const float*)d_in[27];

    const int N = in_sizes[2];
    const int E = in_sizes[1] / 2;
    const int G = out_size;
    const int NBUCK = (N + 511) >> BSH;
    const int C = (E + NBLK - 1) / NBLK;

    // ---------- workspace layout ----------
    int* csr       = (int*)d_ws;               // E
    int* row_start = csr + E;                  // N+64
    int* bpack     = row_start + N + 64;       // E
    int* ghist     = bpack + E;                // NBLK*256
    int* total     = ghist + NBLK * 256;       // 256
    int* bbase     = total + 256;              // 272
    // --- contiguous zero-init region ---
    float* stats   = (float*)(bbase + 272);    // 3*128
    float* pool    = stats + 384;              // G*64
    float* cnt     = pool + (size_t)G * HD;    // G
    // --- end zero region ---
    size_t NH = (size_t)N * HD;
    u16* hA        = (u16*)(cnt + G);          // N*64 bf16
    u16* hB        = hA + NH;                  // N*64 bf16

    const int TB = 256;
    int fusedGrid = (N + 127) / 128;
    size_t zeroBytes = (size_t)(384 + (size_t)G * HD + G) * sizeof(float);

    // ---------- CSR build (deterministic two-pass bucket sort) ----------
    hipMemsetAsync(stats, 0, zeroBytes, stream);
    hist_kernel<<<NBLK, 256, 0, stream>>>(ei, ghist, E, C);
    colscan_kernel<<<NBUCK, 256, 0, stream>>>(ghist, total);
    base_kernel<<<1, 256, 0, stream>>>(total, bbase, NBUCK);
    scatter_kernel<<<NBLK, 256, 0, stream>>>(ei, ghist, bbase, bpack, E, C);
    csrbuild_kernel<<<NBUCK, 256, 0, stream>>>(bpack, bbase, row_start, csr, N);

    // ---------- layer 1: x(16,f32) -> hA(bf16), stats1 (gather fused) ----------
    fused_mlp_kernel<16, false><<<fusedGrid, TB, 0, stream>>>(
        x, row_start, csr, W1a, b1a, W1b, b1b, e1, nullptr, nullptr, nullptr, hA, stats, N);

    // ---------- layer 2: hA(bf16) -> hB(bf16), BN1 folded (gather fused) ----------
    fused_mlp_kernel<64, true><<<fusedGrid, TB, 0, stream>>>(
        hA, row_start, csr, W2a, b2a, W2b, b2b, e2, stats, g1, be1, hB, stats + 128, N);

    // ---------- layer 3: hB(bf16) -> hA(bf16), BN2 folded (gather fused) ----------
    fused_mlp_kernel<64, true><<<fusedGrid, TB, 0, stream>>>(
        hB, row_start, csr, W3a, b3a, W3b, b3b, e3, stats + 128, g2, be2, hA, stats + 256, N);

    // ---------- pool raw h3 (BN3 affine applied in readout) ----------
    int poolWaves = (N + 15) / 16;
    pool_seg_kernel<<<(poolWaves * 64 + TB - 1) / TB, TB, 0, stream>>>(hA, batch, pool, cnt, N);
    readout_kernel<<<G, 64, 0, stream>>>(pool, cnt, stats + 256, g3, be3,
                                         Wf1, bf1, Wf2, bf2, (float*)d_out, N);
}

// Round 11
// 406.499 us; speedup vs baseline: 1.0878x; 1.0878x over previous
//
#include <hip/hip_runtime.h>
#include <hip/hip_bf16.h>

// GIN net, round 11: revert to r9 structure (r10 in-kernel gather fusion
// regressed: barrier-coupled degree imbalance at 3 blocks/CU). Changes vs r9:
// (1) fused_mlp prefetches next-iter feature loads (and iter-0 loads hide
// under weight staging); (2) layer-3 MLP pools in its epilogue (POOL template)
// -> h3 never stored, pool kernel deleted. bf16 features, bucket-sort CSR.

#define HD 64
#define NBLK 256
#define BSH 9        // bucket = 512 nodes; requires N <= 131072

typedef unsigned short u16;

__device__ __forceinline__ float bf2f(u16 u) {
    return __uint_as_float(((unsigned int)u) << 16);
}
__device__ __forceinline__ u16 f2bf(float f) {       // round-to-nearest-even
    unsigned int u = __float_as_uint(f);
    unsigned int r = 0x7FFFu + ((u >> 16) & 1u);
    return (u16)((u + r) >> 16);
}

// ================= CSR build: deterministic two-pass bucket sort =================
__global__ void hist_kernel(const int* __restrict__ ei, int* __restrict__ ghist, int E, int C) {
    __shared__ int lh[256];
    int b = blockIdx.x, tid = threadIdx.x;
    lh[tid] = 0;
    __syncthreads();
    int beg = b * C, end = min(beg + C, E);
    for (int i = beg + tid; i < end; i += 256) atomicAdd(&lh[ei[E + i] >> BSH], 1);
    __syncthreads();
    ghist[b * 256 + tid] = lh[tid];
}

__global__ void colscan_kernel(int* __restrict__ ghist, int* __restrict__ total) {
    __shared__ int s[256];
    int k = blockIdx.x, b = threadIdx.x;
    int v = ghist[b * 256 + k];
    s[b] = v;
    __syncthreads();
    for (int off = 1; off < 256; off <<= 1) {
        int u = (b >= off) ? s[b - off] : 0;
        __syncthreads();
        s[b] += u;
        __syncthreads();
    }
    ghist[b * 256 + k] = s[b] - v;
    if (b == 255) total[k] = s[255];
}

__global__ void base_kernel(const int* __restrict__ total, int* __restrict__ bbase, int NBUCK) {
    __shared__ int s[256];
    int t = threadIdx.x;
    int v = (t < NBUCK) ? total[t] : 0;
    s[t] = v;
    __syncthreads();
    for (int off = 1; off < 256; off <<= 1) {
        int u = (t >= off) ? s[t - off] : 0;
        __syncthreads();
        s[t] += u;
        __syncthreads();
    }
    if (t == 0) bbase[0] = 0;
    bbase[t + 1] = s[t];
}

__global__ void scatter_kernel(const int* __restrict__ ei, const int* __restrict__ ghist,
                               const int* __restrict__ bbase, int* __restrict__ bpack,
                               int E, int C) {
    __shared__ int lcur[256];
    int b = blockIdx.x, tid = threadIdx.x;
    lcur[tid] = bbase[tid] + ghist[b * 256 + tid];
    __syncthreads();
    int beg = b * C, end = min(beg + C, E);
    for (int i = beg + tid; i < end; i += 256) {
        int src = ei[i], dst = ei[E + i];
        int pos = atomicAdd(&lcur[dst >> BSH], 1);
        bpack[pos] = src | ((dst & 511) << 17);
    }
}

__global__ void csrbuild_kernel(const int* __restrict__ bpack, const int* __restrict__ bbase,
                                int* __restrict__ row_start, int* __restrict__ csr, int N) {
    __shared__ int h[512], s[512], lc[512];
    int k = blockIdx.x, tid = threadIdx.x;
    int beg = bbase[k], end = bbase[k + 1];
    h[tid] = 0; h[tid + 256] = 0;
    __syncthreads();
    for (int i = beg + tid; i < end; i += 256) atomicAdd(&h[(bpack[i] >> 17) & 511], 1);
    __syncthreads();
    s[tid] = h[tid]; s[tid + 256] = h[tid + 256];
    __syncthreads();
    for (int off = 1; off < 512; off <<= 1) {
        int v0 = (tid >= off) ? s[tid - off] : 0;
        int t1 = tid + 256;
        int v1 = (t1 >= off) ? s[t1 - off] : 0;
        __syncthreads();
        s[tid] += v0; s[t1] += v1;
        __syncthreads();
    }
    int e0 = s[tid] - h[tid], e1 = s[tid + 256] - h[tid + 256];
    lc[tid] = e0; lc[tid + 256] = e1;
    int n0 = (k << BSH) + tid, n1 = (k << BSH) + tid + 256;
    if (n0 < N) row_start[n0] = beg + e0;
    if (n1 < N) row_start[n1] = beg + e1;
    if (k == gridDim.x - 1 && tid == 0) row_start[N] = end;
    __syncthreads();
    for (int i = beg + tid; i < end; i += 256) {
        int v = bpack[i];
        int pos = beg + atomicAdd(&lc[(v >> 17) & 511], 1);
        csr[pos] = v & 0x1FFFF;
    }
}

// ======== gather64: bf16 rows, 16 lanes/node, ushort4/lane, 4-wide ILP ========
__global__ void gather64_kernel(const u16* __restrict__ x, const int* __restrict__ rs,
                                const int* __restrict__ csr, float* __restrict__ aggr, int N) {
    int lane = threadIdx.x & 63;
    int l4 = lane & 15;
    int wave = (blockIdx.x * blockDim.x + threadIdx.x) >> 6;
    int n = wave * 4 + (lane >> 4);
    if (n >= N) return;
    int beg = rs[n], end = rs[n + 1];
    const u16* xb = x + (size_t)l4 * 4;
    float a0x = 0, a0y = 0, a0z = 0, a0w = 0;
    float a1x = 0, a1y = 0, a1z = 0, a1w = 0;
    float a2x = 0, a2y = 0, a2z = 0, a2w = 0;
    float a3x = 0, a3y = 0, a3z = 0, a3w = 0;
    for (int base = beg; base < end; base += 16) {
        int cnt = end - base; if (cnt > 16) cnt = 16;
        int e = (l4 < cnt) ? csr[base + l4] : 0;
        int j = 0;
        for (; j + 4 <= cnt; j += 4) {
            int s0 = __shfl(e, j + 0, 16);
            int s1 = __shfl(e, j + 1, 16);
            int s2 = __shfl(e, j + 2, 16);
            int s3 = __shfl(e, j + 3, 16);
            ushort4 u0 = *(const ushort4*)(xb + (size_t)s0 * 64);
            ushort4 u1 = *(const ushort4*)(xb + (size_t)s1 * 64);
            ushort4 u2 = *(const ushort4*)(xb + (size_t)s2 * 64);
            ushort4 u3 = *(const ushort4*)(xb + (size_t)s3 * 64);
            a0x += bf2f(u0.x); a0y += bf2f(u0.y); a0z += bf2f(u0.z); a0w += bf2f(u0.w);
            a1x += bf2f(u1.x); a1y += bf2f(u1.y); a1z += bf2f(u1.z); a1w += bf2f(u1.w);
            a2x += bf2f(u2.x); a2y += bf2f(u2.y); a2z += bf2f(u2.z); a2w += bf2f(u2.w);
            a3x += bf2f(u3.x); a3y += bf2f(u3.y); a3z += bf2f(u3.z); a3w += bf2f(u3.w);
        }
        for (; j < cnt; j++) {
            int s = __shfl(e, j, 16);
            ushort4 u = *(const ushort4*)(xb + (size_t)s * 64);
            a0x += bf2f(u.x); a0y += bf2f(u.y); a0z += bf2f(u.z); a0w += bf2f(u.w);
        }
    }
    float4 o;
    o.x = (a0x + a1x) + (a2x + a3x);
    o.y = (a0y + a1y) + (a2y + a3y);
    o.z = (a0z + a1z) + (a2z + a3z);
    o.w = (a0w + a1w) + (a2w + a3w);
    *reinterpret_cast<float4*>(aggr + (size_t)n * 64 + l4 * 4) = o;
}

// gather16: layer-1 input x is f32
__global__ void gather16_kernel(const float* __restrict__ x, const int* __restrict__ rs,
                                const int* __restrict__ csr, float* __restrict__ aggr, int N) {
    int lane = threadIdx.x & 63;
    int l4 = lane & 3;
    int wave = (blockIdx.x * blockDim.x + threadIdx.x) >> 6;
    int n = wave * 16 + (lane >> 2);
    if (n >= N) return;
    int beg = rs[n], end = rs[n + 1];
    const float* xb = x + (size_t)l4 * 4;
    float a0x = 0, a0y = 0, a0z = 0, a0w = 0;
    float a1x = 0, a1y = 0, a1z = 0, a1w = 0;
    float a2x = 0, a2y = 0, a2z = 0, a2w = 0;
    float a3x = 0, a3y = 0, a3z = 0, a3w = 0;
    for (int base = beg; base < end; base += 4) {
        int cnt = end - base; if (cnt > 4) cnt = 4;
        int e = (l4 < cnt) ? csr[base + l4] : 0;
        if (cnt == 4) {
            int s0 = __shfl(e, 0, 4);
            int s1 = __shfl(e, 1, 4);
            int s2 = __shfl(e, 2, 4);
            int s3 = __shfl(e, 3, 4);
            float4 v0 = *(const float4*)(xb + (size_t)s0 * 16);
            float4 v1 = *(const float4*)(xb + (size_t)s1 * 16);
            float4 v2 = *(const float4*)(xb + (size_t)s2 * 16);
            float4 v3 = *(const float4*)(xb + (size_t)s3 * 16);
            a0x += v0.x; a0y += v0.y; a0z += v0.z; a0w += v0.w;
            a1x += v1.x; a1y += v1.y; a1z += v1.z; a1w += v1.w;
            a2x += v2.x; a2y += v2.y; a2z += v2.z; a2w += v2.w;
            a3x += v3.x; a3y += v3.y; a3z += v3.z; a3w += v3.w;
        } else {
            for (int j = 0; j < cnt; j++) {
                int s = __shfl(e, j, 4);
                float4 v = *(const float4*)(xb + (size_t)s * 16);
                a0x += v.x; a0y += v.y; a0z += v.z; a0w += v.w;
            }
        }
    }
    float4 o;
    o.x = (a0x + a1x) + (a2x + a3x);
    o.y = (a0y + a1y) + (a2y + a3y);
    o.z = (a0z + a1z) + (a2z + a3z);
    o.w = (a0w + a1w) + (a2w + a3w);
    *reinterpret_cast<float4*>(aggr + (size_t)n * 16 + l4 * 4) = o;
}

// ======== fused MLP: 4x4 register tile, k-major LDS, BN fold inlined,
//          next-iter prefetch; POOL mode pools in epilogue (no h store) ========
template <int DIN, bool AFF, bool POOL>
__launch_bounds__(256)
__global__ void fused_mlp_kernel(const void* __restrict__ xin_, const float* __restrict__ aggr,
                                 const int* __restrict__ rs, const int* __restrict__ batch,
                                 const float* __restrict__ Wa, const float* __restrict__ ba,
                                 const float* __restrict__ Wb, const float* __restrict__ bb,
                                 const float* __restrict__ epsp,
                                 const float* __restrict__ statsPrev,
                                 const float* __restrict__ gPrev, const float* __restrict__ bePrev,
                                 u16* __restrict__ hout, float* __restrict__ stats,
                                 float* __restrict__ pool, float* __restrict__ cnt, int N) {
    __shared__ float Wa_s[DIN * 64];
    __shared__ float Wb_s[64 * 64];
    __shared__ float zts[64 * 68];
    __shared__ float statS[128];
    __shared__ float degS[64];
    __shared__ float aS[64], cS[64], uS[64];

    const int tid = threadIdx.x;
    const int tc = tid & 15;
    const int tn = tid >> 4;
    const float* xinF = (const float*)xin_;
    const u16*   xinB = (const u16*)xin_;

    const int ITER = 2;
    int blockBase = blockIdx.x * (64 * ITER);

    // ---- prologue: issue iter-0 feature loads (latency hides under staging) ----
    ushort4 xuP[4]; float4 avP[4];     // DIN==64
    float4  xvP, av16P;                // DIN==16
    if (DIN == 64) {
#pragma unroll
        for (int i = 0; i < 4; ++i) {
            int node = blockBase + tn * 4 + i;
            xuP[i] = make_ushort4(0, 0, 0, 0);
            avP[i] = make_float4(0, 0, 0, 0);
            if (node < N) {
                xuP[i] = *(const ushort4*)&xinB[(size_t)node * 64 + tc * 4];
                avP[i] = *(const float4*)&aggr[(size_t)node * 64 + tc * 4];
            }
        }
    } else {
        int node = blockBase + tn * 4 + (tc >> 2);
        xvP = make_float4(0, 0, 0, 0);
        av16P = make_float4(0, 0, 0, 0);
        if (node < N) {
            xvP = *(const float4*)&xinF[(size_t)node * 16 + (tc & 3) * 4];
            av16P = *(const float4*)&aggr[(size_t)node * 16 + (tc & 3) * 4];
        }
    }

    if (AFF) {
        if (tid < 64) {
            float invN = 1.0f / (float)N;
            float mu = statsPrev[tid] * invN;
            float var = statsPrev[64 + tid] * invN - mu * mu;
            float inv = rsqrtf(var + 1e-5f);
            float a = gPrev[tid] * inv;
            aS[tid] = a;
            cS[tid] = bePrev[tid] - mu * a;
        }
        __syncthreads();
        for (int i = tid; i < DIN * 64; i += 256) Wa_s[i] = aS[i >> 6] * Wa[i];
        if (tid < 64) {
            float s = 0.0f;
            for (int k = 0; k < 64; k++) s = fmaf(cS[k], Wa[k * 64 + tid], s);
            uS[tid] = s;
        }
    } else {
        for (int i = tid; i < DIN * 64; i += 256) Wa_s[i] = Wa[i];
    }
    for (int i = tid; i < 64 * 64; i += 256) Wb_s[i] = Wb[i];
    if (tid < 128) statS[tid] = 0.0f;
    const float e1 = 1.0f + epsp[0];
    __syncthreads();

    float4 t4;
    t4 = *(const float4*)&ba[tc * 4];
    const float bav[4] = {t4.x, t4.y, t4.z, t4.w};
    t4 = *(const float4*)&bb[tc * 4];
    const float bbv[4] = {t4.x, t4.y, t4.z, t4.w};
    float uv[4] = {0, 0, 0, 0};
    if (AFF) { uv[0] = uS[tc * 4]; uv[1] = uS[tc * 4 + 1]; uv[2] = uS[tc * 4 + 2]; uv[3] = uS[tc * 4 + 3]; }

    float sv[4] = {0, 0, 0, 0}, qv[4] = {0, 0, 0, 0};

    for (int it = 0; it < ITER; ++it) {
        int gbase = blockBase + it * 64;
        // ---- compute zr from prefetched regs ----
        float zr[4][4];
        if (DIN == 64) {
#pragma unroll
            for (int i = 0; i < 4; ++i) {
                zr[i][0] = fmaf(e1, bf2f(xuP[i].x), avP[i].x);
                zr[i][1] = fmaf(e1, bf2f(xuP[i].y), avP[i].y);
                zr[i][2] = fmaf(e1, bf2f(xuP[i].z), avP[i].z);
                zr[i][3] = fmaf(e1, bf2f(xuP[i].w), avP[i].w);
            }
        } else {
            zr[0][0] = fmaf(e1, xvP.x, av16P.x);
            zr[0][1] = fmaf(e1, xvP.y, av16P.y);
            zr[0][2] = fmaf(e1, xvP.z, av16P.z);
            zr[0][3] = fmaf(e1, xvP.w, av16P.w);
        }
        // ---- prefetch next iter ----
        if (it + 1 < ITER) {
            int nbase = gbase + 64;
            if (DIN == 64) {
#pragma unroll
                for (int i = 0; i < 4; ++i) {
                    int node = nbase + tn * 4 + i;
                    ushort4 xu = make_ushort4(0, 0, 0, 0);
                    float4 av = make_float4(0, 0, 0, 0);
                    if (node < N) {
                        xu = *(const ushort4*)&xinB[(size_t)node * 64 + tc * 4];
                        av = *(const float4*)&aggr[(size_t)node * 64 + tc * 4];
                    }
                    xuP[i] = xu; avP[i] = av;   // safe: zr already computed
                }
            } else {
                int node = nbase + tn * 4 + (tc >> 2);
                float4 xv = make_float4(0, 0, 0, 0), av = make_float4(0, 0, 0, 0);
                if (node < N) {
                    xv = *(const float4*)&xinF[(size_t)node * 16 + (tc & 3) * 4];
                    av = *(const float4*)&aggr[(size_t)node * 16 + (tc & 3) * 4];
                }
                xvP = xv; av16P = av;
            }
        }
        float dg[4];
        if (AFF && tid < 64) {
            int node = gbase + tid;
            degS[tid] = (node < N) ? (float)(rs[node + 1] - rs[node]) : 0.0f;
        }
        __syncthreads();                       // bar0
        if (DIN == 64) {
#pragma unroll
            for (int j = 0; j < 4; ++j) {
                float4 w = {zr[0][j], zr[1][j], zr[2][j], zr[3][j]};
                *(float4*)&zts[(tc * 4 + j) * 68 + tn * 4] = w;
            }
        } else {
#pragma unroll
            for (int j = 0; j < 4; ++j)
                zts[((tc & 3) * 4 + j) * 68 + tn * 4 + (tc >> 2)] = zr[0][j];
        }
        __syncthreads();                       // bar1
        if (AFF) {
#pragma unroll
            for (int i = 0; i < 4; ++i) dg[i] = e1 + degS[tn * 4 + i];
        }
        float ac[4][4];
#pragma unroll
        for (int i = 0; i < 4; ++i)
#pragma unroll
            for (int j = 0; j < 4; ++j)
                ac[i][j] = AFF ? fmaf(dg[i], uv[j], bav[j]) : bav[j];
#pragma unroll 8
        for (int k = 0; k < DIN; ++k) {
            float4 zv = *(const float4*)&zts[k * 68 + tn * 4];
            float4 wv = *(const float4*)&Wa_s[k * 64 + tc * 4];
            const float zf[4] = {zv.x, zv.y, zv.z, zv.w};
            const float wf[4] = {wv.x, wv.y, wv.z, wv.w};
#pragma unroll
            for (int i = 0; i < 4; ++i)
#pragma unroll
                for (int j = 0; j < 4; ++j)
                    ac[i][j] = fmaf(zf[i], wf[j], ac[i][j]);
        }
#pragma unroll
        for (int i = 0; i < 4; ++i)
#pragma unroll
            for (int j = 0; j < 4; ++j)
                ac[i][j] = fmaxf(ac[i][j], 0.0f);
        __syncthreads();                       // bar2
#pragma unroll
        for (int j = 0; j < 4; ++j) {
            float4 w = {ac[0][j], ac[1][j], ac[2][j], ac[3][j]};
            *(float4*)&zts[(tc * 4 + j) * 68 + tn * 4] = w;
        }
        __syncthreads();                       // bar3
        float hc[4][4];
#pragma unroll
        for (int i = 0; i < 4; ++i)
#pragma unroll
            for (int j = 0; j < 4; ++j)
                hc[i][j] = bbv[j];
#pragma unroll 8
        for (int k = 0; k < 64; ++k) {
            float4 tv = *(const float4*)&zts[k * 68 + tn * 4];
            float4 wv = *(const float4*)&Wb_s[k * 64 + tc * 4];
            const float tf[4] = {tv.x, tv.y, tv.z, tv.w};
            const float wf[4] = {wv.x, wv.y, wv.z, wv.w};
#pragma unroll
            for (int i = 0; i < 4; ++i)
#pragma unroll
                for (int j = 0; j < 4; ++j)
                    hc[i][j] = fmaf(tf[i], wf[j], hc[i][j]);
        }
        // ---- epilogue: store bf16 h OR pool directly ----
        if (POOL) {
            int curg = -1; float p0 = 0, p1 = 0, p2 = 0, p3 = 0; int run = 0;
#pragma unroll
            for (int i = 0; i < 4; ++i) {
                int node = gbase + tn * 4 + i;
                if (node < N) {
                    float o0 = fmaxf(hc[i][0], 0.0f), o1 = fmaxf(hc[i][1], 0.0f);
                    float o2 = fmaxf(hc[i][2], 0.0f), o3 = fmaxf(hc[i][3], 0.0f);
                    sv[0] += o0; sv[1] += o1; sv[2] += o2; sv[3] += o3;
                    qv[0] += o0 * o0; qv[1] += o1 * o1; qv[2] += o2 * o2; qv[3] += o3 * o3;
                    int gid = batch[node];
                    if (gid != curg) {
                        if (curg >= 0) {
                            unsafeAtomicAdd(&pool[(size_t)curg * 64 + tc * 4 + 0], p0);
                            unsafeAtomicAdd(&pool[(size_t)curg * 64 + tc * 4 + 1], p1);
                            unsafeAtomicAdd(&pool[(size_t)curg * 64 + tc * 4 + 2], p2);
                            unsafeAtomicAdd(&pool[(size_t)curg * 64 + tc * 4 + 3], p3);
                            if (tc == 0) unsafeAtomicAdd(&cnt[curg], (float)run);
                        }
                        curg = gid; p0 = p1 = p2 = p3 = 0.0f; run = 0;
                    }
                    p0 += o0; p1 += o1; p2 += o2; p3 += o3; run++;
                }
            }
            if (curg >= 0) {
                unsafeAtomicAdd(&pool[(size_t)curg * 64 + tc * 4 + 0], p0);
                unsafeAtomicAdd(&pool[(size_t)curg * 64 + tc * 4 + 1], p1);
                unsafeAtomicAdd(&pool[(size_t)curg * 64 + tc * 4 + 2], p2);
                unsafeAtomicAdd(&pool[(size_t)curg * 64 + tc * 4 + 3], p3);
                if (tc == 0) unsafeAtomicAdd(&cnt[curg], (float)run);
            }
        } else {
#pragma unroll
            for (int i = 0; i < 4; ++i) {
                int node = gbase + tn * 4 + i;
                if (node < N) {
                    float o0 = fmaxf(hc[i][0], 0.0f), o1 = fmaxf(hc[i][1], 0.0f);
                    float o2 = fmaxf(hc[i][2], 0.0f), o3 = fmaxf(hc[i][3], 0.0f);
                    ushort4 ob = {f2bf(o0), f2bf(o1), f2bf(o2), f2bf(o3)};
                    *(ushort4*)&hout[(size_t)node * 64 + tc * 4] = ob;
                    sv[0] += o0; sv[1] += o1; sv[2] += o2; sv[3] += o3;
                    qv[0] += o0 * o0; qv[1] += o1 * o1; qv[2] += o2 * o2; qv[3] += o3 * o3;
                }
            }
        }
    }
#pragma unroll
    for (int off = 16; off < 64; off <<= 1) {
#pragma unroll
        for (int j = 0; j < 4; ++j) {
            sv[j] += __shfl_xor(sv[j], off);
            qv[j] += __shfl_xor(qv[j], off);
        }
    }
    if ((tid & 63) < 16) {
#pragma unroll
        for (int j = 0; j < 4; ++j) {
            atomicAdd(&statS[tc * 4 + j], sv[j]);
            atomicAdd(&statS[64 + tc * 4 + j], qv[j]);
        }
    }
    __syncthreads();
    if (tid < 128) unsafeAtomicAdd(&stats[tid], statS[tid]);
}

// ================= readout (applies BN3 affine to pooled mean) =================
__global__ void readout_kernel(const float* __restrict__ pool, const float* __restrict__ cnt,
                               const float* __restrict__ stats, const float* __restrict__ g3,
                               const float* __restrict__ be3,
                               const float* __restrict__ Wf1, const float* __restrict__ bf1,
                               const float* __restrict__ Wf2, const float* __restrict__ bf2,
                               float* __restrict__ out, int N) {
    int gb = blockIdx.x;
    int t = threadIdx.x;  // 64 threads
    float invN = 1.0f / (float)N;
    float mu = stats[t] * invN;
    float var = stats[64 + t] * invN - mu * mu;
    float inv = rsqrtf(var + 1e-5f);
    float a = g3[t] * inv;
    float c = be3[t] - mu * a;
    float cn = cnt[gb];
    float p = (cn > 0.0f) ? (a * (pool[(size_t)gb * 64 + t] / cn) + c) : 0.0f;
    float o = 0.0f;
#pragma unroll
    for (int j = 0; j < 10; j++) {
        float part = p * Wf1[t * 10 + j];
#pragma unroll
        for (int off = 32; off > 0; off >>= 1) part += __shfl_down(part, off);
        float z = fmaxf(part + bf1[j], 0.0f);   // valid on lane 0 only
        o = fmaf(z, Wf2[j], o);
    }
    if (t == 0) out[gb] = o + bf2[0];
}

extern "C" void kernel_launch(void* const* d_in, const int* in_sizes, int n_in,
                              void* d_out, int out_size, void* d_ws, size_t ws_size,
                              hipStream_t stream) {
    const float* x      = (const float*)d_in[0];
    const int*   ei     = (const int*)d_in[1];
    const int*   batch  = (const int*)d_in[2];
    const float* W1a = (const float*)d_in[3];  const float* b1a = (const float*)d_in[4];
    const float* W1b = (const float*)d_in[5];  const float* b1b = (const float*)d_in[6];
    const float* e1  = (const float*)d_in[7];  const float* g1  = (const float*)d_in[8];
    const float* be1 = (const float*)d_in[9];
    const float* W2a = (const float*)d_in[10]; const float* b2a = (const float*)d_in[11];
    const float* W2b = (const float*)d_in[12]; const float* b2b = (const float*)d_in[13];
    const float* e2  = (const float*)d_in[14]; const float* g2  = (const float*)d_in[15];
    const float* be2 = (const float*)d_in[16];
    const float* W3a = (const float*)d_in[17]; const float* b3a = (const float*)d_in[18];
    const float* W3b = (const float*)d_in[19]; const float* b3b = (const float*)d_in[20];
    const float* e3  = (const float*)d_in[21]; const float* g3  = (const float*)d_in[22];
    const float* be3 = (const float*)d_in[23];
    const float* Wf1 = (const float*)d_in[24]; const float* bf1 = (const float*)d_in[25];
    const float* Wf2 = (const float*)d_in[26]; const float* bf2 = (const float*)d_in[27];

    const int N = in_sizes[2];
    const int E = in_sizes[1] / 2;
    const int G = out_size;
    const int NBUCK = (N + 511) >> BSH;
    const int C = (E + NBLK - 1) / NBLK;

    // ---------- workspace layout ----------
    int* csr       = (int*)d_ws;               // E
    int* row_start = csr + E;                  // N+64
    int* bpack     = row_start + N + 64;       // E
    int* ghist     = bpack + E;                // NBLK*256
    int* total     = ghist + NBLK * 256;       // 256
    int* bbase     = total + 256;              // 272
    // --- contiguous zero-init region ---
    float* stats   = (float*)(bbase + 272);    // 3*128
    float* pool    = stats + 384;              // G*64
    float* cnt     = pool + (size_t)G * HD;    // G
    // --- end zero region ---
    float* aggr    = cnt + G;                  // N*64 f32
    size_t NH = (size_t)N * HD;
    u16* hA        = (u16*)(aggr + NH);        // N*64 bf16
    u16* hB        = hA + NH;                  // N*64 bf16

    const int TB = 256;
    int fusedGrid = (N + 127) / 128;
    size_t zeroBytes = (size_t)(384 + (size_t)G * HD + G) * sizeof(float);

    // ---------- CSR build (deterministic two-pass bucket sort) ----------
    hipMemsetAsync(stats, 0, zeroBytes, stream);
    hist_kernel<<<NBLK, 256, 0, stream>>>(ei, ghist, E, C);
    colscan_kernel<<<NBUCK, 256, 0, stream>>>(ghist, total);
    base_kernel<<<1, 256, 0, stream>>>(total, bbase, NBUCK);
    scatter_kernel<<<NBLK, 256, 0, stream>>>(ei, ghist, bbase, bpack, E, C);
    csrbuild_kernel<<<NBUCK, 256, 0, stream>>>(bpack, bbase, row_start, csr, N);

    // ---------- layer 1: x(16,f32) -> hA(bf16), stats1 ----------
    gather16_kernel<<<((N + 15) / 16 * 64 + TB - 1) / TB, TB, 0, stream>>>(x, row_start, csr, aggr, N);
    fused_mlp_kernel<16, false, false><<<fusedGrid, TB, 0, stream>>>(
        x, aggr, row_start, batch, W1a, b1a, W1b, b1b, e1,
        nullptr, nullptr, nullptr, hA, stats, nullptr, nullptr, N);

    // ---------- layer 2: hA(bf16) -> hB(bf16), BN1 folded ----------
    gather64_kernel<<<((N + 3) / 4 * 64 + TB - 1) / TB, TB, 0, stream>>>(hA, row_start, csr, aggr, N);
    fused_mlp_kernel<64, true, false><<<fusedGrid, TB, 0, stream>>>(
        hA, aggr, row_start, batch, W2a, b2a, W2b, b2b, e2,
        stats, g1, be1, hB, stats + 128, nullptr, nullptr, N);

    // ---------- layer 3: hB(bf16) -> pooled directly (POOL), BN2 folded ----------
    gather64_kernel<<<((N + 3) / 4 * 64 + TB - 1) / TB, TB, 0, stream>>>(hB, row_start, csr, aggr, N);
    fused_mlp_kernel<64, true, true><<<fusedGrid, TB, 0, stream>>>(
        hB, aggr, row_start, batch, W3a, b3a, W3b, b3b, e3,
        stats + 128, g2, be2, hA /*unused*/, stats + 256, pool, cnt, N);

    // ---------- readout (BN3 affine on pooled mean) ----------
    readout_kernel<<<G, 64, 0, stream>>>(pool, cnt, stats + 256, g3, be3,
                                         Wf1, bf1, Wf2, bf2, (float*)d_out, N);
}

// Round 13
// 383.280 us; speedup vs baseline: 1.1537x; 1.0606x over previous
//
#include <hip/hip_runtime.h>
#include <hip/hip_bf16.h>

// GIN net, round 13: r12's bf16 weights+aggr overdrew the error budget
// (4.88e-3 > 4.06e-3). Revert to r11 numerics (f32 weights, f32 aggr) but
// keep the occupancy attack a different way: ONE f32 weight LDS buffer
// time-shared (Wa for Phase B; Wb register-prefetched at entry, written into
// the same buffer after the z-consumed barrier) -> 51.7->34.5KB LDS ->
// 4 blocks/CU. ITER=1 (grid 1563), SREP stats replication, POOL epilogue.

#define HD 64
#define NBLK 256
#define BSH 9        // bucket = 512 nodes; requires N <= 131072
#define SREP 8       // stats replication

typedef unsigned short u16;
typedef unsigned int u32;

__device__ __forceinline__ float bf2f(u16 u) {
    return __uint_as_float(((u32)u) << 16);
}
__device__ __forceinline__ u16 f2bf(float f) {       // round-to-nearest-even
    u32 u = __float_as_uint(f);
    u32 r = 0x7FFFu + ((u >> 16) & 1u);
    return (u16)((u + r) >> 16);
}

// ================= CSR build: deterministic two-pass bucket sort =================
__global__ void hist_kernel(const int* __restrict__ ei, int* __restrict__ ghist, int E, int C) {
    __shared__ int lh[256];
    int b = blockIdx.x, tid = threadIdx.x;
    lh[tid] = 0;
    __syncthreads();
    int beg = b * C, end = min(beg + C, E);
    for (int i = beg + tid; i < end; i += 256) atomicAdd(&lh[ei[E + i] >> BSH], 1);
    __syncthreads();
    ghist[b * 256 + tid] = lh[tid];
}

__global__ void colscan_kernel(int* __restrict__ ghist, int* __restrict__ total) {
    __shared__ int s[256];
    int k = blockIdx.x, b = threadIdx.x;
    int v = ghist[b * 256 + k];
    s[b] = v;
    __syncthreads();
    for (int off = 1; off < 256; off <<= 1) {
        int u = (b >= off) ? s[b - off] : 0;
        __syncthreads();
        s[b] += u;
        __syncthreads();
    }
    ghist[b * 256 + k] = s[b] - v;
    if (b == 255) total[k] = s[255];
}

__global__ void base_kernel(const int* __restrict__ total, int* __restrict__ bbase, int NBUCK) {
    __shared__ int s[256];
    int t = threadIdx.x;
    int v = (t < NBUCK) ? total[t] : 0;
    s[t] = v;
    __syncthreads();
    for (int off = 1; off < 256; off <<= 1) {
        int u = (t >= off) ? s[t - off] : 0;
        __syncthreads();
        s[t] += u;
        __syncthreads();
    }
    if (t == 0) bbase[0] = 0;
    bbase[t + 1] = s[t];
}

__global__ void scatter_kernel(const int* __restrict__ ei, const int* __restrict__ ghist,
                               const int* __restrict__ bbase, int* __restrict__ bpack,
                               int E, int C) {
    __shared__ int lcur[256];
    int b = blockIdx.x, tid = threadIdx.x;
    lcur[tid] = bbase[tid] + ghist[b * 256 + tid];
    __syncthreads();
    int beg = b * C, end = min(beg + C, E);
    for (int i = beg + tid; i < end; i += 256) {
        int src = ei[i], dst = ei[E + i];
        int pos = atomicAdd(&lcur[dst >> BSH], 1);
        bpack[pos] = src | ((dst & 511) << 17);
    }
}

__global__ void csrbuild_kernel(const int* __restrict__ bpack, const int* __restrict__ bbase,
                                int* __restrict__ row_start, int* __restrict__ csr, int N) {
    __shared__ int h[512], s[512], lc[512];
    int k = blockIdx.x, tid = threadIdx.x;
    int beg = bbase[k], end = bbase[k + 1];
    h[tid] = 0; h[tid + 256] = 0;
    __syncthreads();
    for (int i = beg + tid; i < end; i += 256) atomicAdd(&h[(bpack[i] >> 17) & 511], 1);
    __syncthreads();
    s[tid] = h[tid]; s[tid + 256] = h[tid + 256];
    __syncthreads();
    for (int off = 1; off < 512; off <<= 1) {
        int v0 = (tid >= off) ? s[tid - off] : 0;
        int t1 = tid + 256;
        int v1 = (t1 >= off) ? s[t1 - off] : 0;
        __syncthreads();
        s[tid] += v0; s[t1] += v1;
        __syncthreads();
    }
    int e0 = s[tid] - h[tid], e1 = s[tid + 256] - h[tid + 256];
    lc[tid] = e0; lc[tid + 256] = e1;
    int n0 = (k << BSH) + tid, n1 = (k << BSH) + tid + 256;
    if (n0 < N) row_start[n0] = beg + e0;
    if (n1 < N) row_start[n1] = beg + e1;
    if (k == gridDim.x - 1 && tid == 0) row_start[N] = end;
    __syncthreads();
    for (int i = beg + tid; i < end; i += 256) {
        int v = bpack[i];
        int pos = beg + atomicAdd(&lc[(v >> 17) & 511], 1);
        csr[pos] = v & 0x1FFFF;
    }
}

// ======== gather64: bf16 rows in, f32 aggr out; 16 lanes/node, 4-wide ILP ========
__global__ void gather64_kernel(const u16* __restrict__ x, const int* __restrict__ rs,
                                const int* __restrict__ csr, float* __restrict__ aggr, int N) {
    int lane = threadIdx.x & 63;
    int l4 = lane & 15;
    int wave = (blockIdx.x * blockDim.x + threadIdx.x) >> 6;
    int n = wave * 4 + (lane >> 4);
    if (n >= N) return;
    int beg = rs[n], end = rs[n + 1];
    const u16* xb = x + (size_t)l4 * 4;
    float a0x = 0, a0y = 0, a0z = 0, a0w = 0;
    float a1x = 0, a1y = 0, a1z = 0, a1w = 0;
    float a2x = 0, a2y = 0, a2z = 0, a2w = 0;
    float a3x = 0, a3y = 0, a3z = 0, a3w = 0;
    for (int base = beg; base < end; base += 16) {
        int cnt = end - base; if (cnt > 16) cnt = 16;
        int e = (l4 < cnt) ? csr[base + l4] : 0;
        int j = 0;
        for (; j + 4 <= cnt; j += 4) {
            int s0 = __shfl(e, j + 0, 16);
            int s1 = __shfl(e, j + 1, 16);
            int s2 = __shfl(e, j + 2, 16);
            int s3 = __shfl(e, j + 3, 16);
            ushort4 u0 = *(const ushort4*)(xb + (size_t)s0 * 64);
            ushort4 u1 = *(const ushort4*)(xb + (size_t)s1 * 64);
            ushort4 u2 = *(const ushort4*)(xb + (size_t)s2 * 64);
            ushort4 u3 = *(const ushort4*)(xb + (size_t)s3 * 64);
            a0x += bf2f(u0.x); a0y += bf2f(u0.y); a0z += bf2f(u0.z); a0w += bf2f(u0.w);
            a1x += bf2f(u1.x); a1y += bf2f(u1.y); a1z += bf2f(u1.z); a1w += bf2f(u1.w);
            a2x += bf2f(u2.x); a2y += bf2f(u2.y); a2z += bf2f(u2.z); a2w += bf2f(u2.w);
            a3x += bf2f(u3.x); a3y += bf2f(u3.y); a3z += bf2f(u3.z); a3w += bf2f(u3.w);
        }
        for (; j < cnt; j++) {
            int s = __shfl(e, j, 16);
            ushort4 u = *(const ushort4*)(xb + (size_t)s * 64);
            a0x += bf2f(u.x); a0y += bf2f(u.y); a0z += bf2f(u.z); a0w += bf2f(u.w);
        }
    }
    float4 o;
    o.x = (a0x + a1x) + (a2x + a3x);
    o.y = (a0y + a1y) + (a2y + a3y);
    o.z = (a0z + a1z) + (a2z + a3z);
    o.w = (a0w + a1w) + (a2w + a3w);
    *reinterpret_cast<float4*>(aggr + (size_t)n * 64 + l4 * 4) = o;
}

// gather16: layer-1 input x is f32; aggr stays f32
__global__ void gather16_kernel(const float* __restrict__ x, const int* __restrict__ rs,
                                const int* __restrict__ csr, float* __restrict__ aggr, int N) {
    int lane = threadIdx.x & 63;
    int l4 = lane & 3;
    int wave = (blockIdx.x * blockDim.x + threadIdx.x) >> 6;
    int n = wave * 16 + (lane >> 2);
    if (n >= N) return;
    int beg = rs[n], end = rs[n + 1];
    const float* xb = x + (size_t)l4 * 4;
    float a0x = 0, a0y = 0, a0z = 0, a0w = 0;
    float a1x = 0, a1y = 0, a1z = 0, a1w = 0;
    float a2x = 0, a2y = 0, a2z = 0, a2w = 0;
    float a3x = 0, a3y = 0, a3z = 0, a3w = 0;
    for (int base = beg; base < end; base += 4) {
        int cnt = end - base; if (cnt > 4) cnt = 4;
        int e = (l4 < cnt) ? csr[base + l4] : 0;
        if (cnt == 4) {
            int s0 = __shfl(e, 0, 4);
            int s1 = __shfl(e, 1, 4);
            int s2 = __shfl(e, 2, 4);
            int s3 = __shfl(e, 3, 4);
            float4 v0 = *(const float4*)(xb + (size_t)s0 * 16);
            float4 v1 = *(const float4*)(xb + (size_t)s1 * 16);
            float4 v2 = *(const float4*)(xb + (size_t)s2 * 16);
            float4 v3 = *(const float4*)(xb + (size_t)s3 * 16);
            a0x += v0.x; a0y += v0.y; a0z += v0.z; a0w += v0.w;
            a1x += v1.x; a1y += v1.y; a1z += v1.z; a1w += v1.w;
            a2x += v2.x; a2y += v2.y; a2z += v2.z; a2w += v2.w;
            a3x += v3.x; a3y += v3.y; a3z += v3.z; a3w += v3.w;
        } else {
            for (int j = 0; j < cnt; j++) {
                int s = __shfl(e, j, 4);
                float4 v = *(const float4*)(xb + (size_t)s * 16);
                a0x += v.x; a0y += v.y; a0z += v.z; a0w += v.w;
            }
        }
    }
    float4 o;
    o.x = (a0x + a1x) + (a2x + a3x);
    o.y = (a0y + a1y) + (a2y + a3y);
    o.z = (a0z + a1z) + (a2z + a3z);
    o.w = (a0w + a1w) + (a2w + a3w);
    *reinterpret_cast<float4*>(aggr + (size_t)n * 16 + l4 * 4) = o;
}

// ======== fused MLP: 4x4 register tile, ONE time-shared f32 weight buffer ========
// W_s holds Wa for Phase B; Wb (register-prefetched) overwrites it for Phase C.
// ITER=1 (64 nodes/block); stats replicated SREP-wide; POOL pools in epilogue.
template <int DIN, bool AFF, bool POOL>
__launch_bounds__(256)
__global__ void fused_mlp_kernel(const void* __restrict__ xin_, const float* __restrict__ aggr,
                                 const int* __restrict__ rs, const int* __restrict__ batch,
                                 const float* __restrict__ Wa, const float* __restrict__ ba,
                                 const float* __restrict__ Wb, const float* __restrict__ bb,
                                 const float* __restrict__ epsp,
                                 const float* __restrict__ statsPrev,
                                 const float* __restrict__ gPrev, const float* __restrict__ bePrev,
                                 u16* __restrict__ hout, float* __restrict__ stats,
                                 float* __restrict__ pool, float* __restrict__ cnt, int N) {
    __shared__ float W_s[64 * 64];     // Wa (Phase B) then Wb (Phase C)
    __shared__ float zts[64 * 68];
    __shared__ float statS[128];
    __shared__ float degS[64];
    __shared__ float aS[64], cS[64], uS[64];

    const int tid = threadIdx.x;
    const int tc = tid & 15;
    const int tn = tid >> 4;
    const float* xinF = (const float*)xin_;
    const u16*   xinB = (const u16*)xin_;

    int blockBase = blockIdx.x * 64;

    // ---- issue feature loads early (latency hides under weight staging) ----
    ushort4 xuP[4]; float4 avP[4];     // DIN==64
    float4  xvP, av16P;                // DIN==16
    if (DIN == 64) {
#pragma unroll
        for (int i = 0; i < 4; ++i) {
            int node = blockBase + tn * 4 + i;
            xuP[i] = make_ushort4(0, 0, 0, 0);
            avP[i] = make_float4(0, 0, 0, 0);
            if (node < N) {
                xuP[i] = *(const ushort4*)&xinB[(size_t)node * 64 + tc * 4];
                avP[i] = *(const float4*)&aggr[(size_t)node * 64 + tc * 4];
            }
        }
    } else {
        int node = blockBase + tn * 4 + (tc >> 2);
        xvP = make_float4(0, 0, 0, 0);
        av16P = make_float4(0, 0, 0, 0);
        if (node < N) {
            xvP = *(const float4*)&xinF[(size_t)node * 16 + (tc & 3) * 4];
            av16P = *(const float4*)&aggr[(size_t)node * 16 + (tc & 3) * 4];
        }
    }
    // ---- prefetch Wb into registers (written to W_s after Phase B) ----
    float wbR[16];
#pragma unroll
    for (int i = 0; i < 16; ++i) wbR[i] = Wb[tid + i * 256];

    // ---- stage Wa into W_s (AFF folds prev BN) ----
    if (AFF) {
        if (tid < 64) {
            float invN = 1.0f / (float)N;
            float s0 = 0, s1 = 0;
#pragma unroll
            for (int r = 0; r < SREP; ++r) {
                s0 += statsPrev[r * 128 + tid];
                s1 += statsPrev[r * 128 + 64 + tid];
            }
            float mu = s0 * invN;
            float var = s1 * invN - mu * mu;
            float inv = rsqrtf(var + 1e-5f);
            float a = gPrev[tid] * inv;
            aS[tid] = a;
            cS[tid] = bePrev[tid] - mu * a;
        }
        __syncthreads();
        for (int i = tid; i < DIN * 64; i += 256) W_s[i] = aS[i >> 6] * Wa[i];
        if (tid < 64) {
            float s = 0.0f;
            for (int k = 0; k < 64; k++) s = fmaf(cS[k], Wa[k * 64 + tid], s);
            uS[tid] = s;
        }
    } else {
        for (int i = tid; i < DIN * 64; i += 256) W_s[i] = Wa[i];
    }
    if (tid < 128) statS[tid] = 0.0f;
    const float e1 = 1.0f + epsp[0];
    if (AFF && tid < 64) {
        int node = blockBase + tid;
        degS[tid] = (node < N) ? (float)(rs[node + 1] - rs[node]) : 0.0f;
    }

    float4 t4;
    t4 = *(const float4*)&ba[tc * 4];
    const float bav[4] = {t4.x, t4.y, t4.z, t4.w};
    t4 = *(const float4*)&bb[tc * 4];
    const float bbv[4] = {t4.x, t4.y, t4.z, t4.w};

    float sv[4] = {0, 0, 0, 0}, qv[4] = {0, 0, 0, 0};

    // ---- z tile -> LDS (k-major transposed) ----
    float zr[4][4];
    if (DIN == 64) {
#pragma unroll
        for (int i = 0; i < 4; ++i) {
            zr[i][0] = fmaf(e1, bf2f(xuP[i].x), avP[i].x);
            zr[i][1] = fmaf(e1, bf2f(xuP[i].y), avP[i].y);
            zr[i][2] = fmaf(e1, bf2f(xuP[i].z), avP[i].z);
            zr[i][3] = fmaf(e1, bf2f(xuP[i].w), avP[i].w);
        }
#pragma unroll
        for (int j = 0; j < 4; ++j) {
            float4 w = {zr[0][j], zr[1][j], zr[2][j], zr[3][j]};
            *(float4*)&zts[(tc * 4 + j) * 68 + tn * 4] = w;
        }
    } else {
        zr[0][0] = fmaf(e1, xvP.x, av16P.x);
        zr[0][1] = fmaf(e1, xvP.y, av16P.y);
        zr[0][2] = fmaf(e1, xvP.z, av16P.z);
        zr[0][3] = fmaf(e1, xvP.w, av16P.w);
#pragma unroll
        for (int j = 0; j < 4; ++j)
            zts[((tc & 3) * 4 + j) * 68 + tn * 4 + (tc >> 2)] = zr[0][j];
    }
    __syncthreads();                       // bar1: z tile + Wa ready
    float uv[4] = {0, 0, 0, 0};
    if (AFF) { uv[0] = uS[tc * 4]; uv[1] = uS[tc * 4 + 1]; uv[2] = uS[tc * 4 + 2]; uv[3] = uS[tc * 4 + 3]; }
    float dg[4];
    if (AFF) {
#pragma unroll
        for (int i = 0; i < 4; ++i) dg[i] = e1 + degS[tn * 4 + i];
    }
    // ---- Phase B: t = relu(z @ Wa + bias) ----
    float ac[4][4];
#pragma unroll
    for (int i = 0; i < 4; ++i)
#pragma unroll
        for (int j = 0; j < 4; ++j)
            ac[i][j] = AFF ? fmaf(dg[i], uv[j], bav[j]) : bav[j];
#pragma unroll 8
    for (int k = 0; k < DIN; ++k) {
        float4 zv = *(const float4*)&zts[k * 68 + tn * 4];
        float4 wv = *(const float4*)&W_s[k * 64 + tc * 4];
        const float zf[4] = {zv.x, zv.y, zv.z, zv.w};
        const float wf[4] = {wv.x, wv.y, wv.z, wv.w};
#pragma unroll
        for (int i = 0; i < 4; ++i)
#pragma unroll
            for (int j = 0; j < 4; ++j)
                ac[i][j] = fmaf(zf[i], wf[j], ac[i][j]);
    }
#pragma unroll
    for (int i = 0; i < 4; ++i)
#pragma unroll
        for (int j = 0; j < 4; ++j)
            ac[i][j] = fmaxf(ac[i][j], 0.0f);
    __syncthreads();                       // bar2: z tile + Wa consumed
    // ---- write t tile AND Wb into LDS ----
#pragma unroll
    for (int j = 0; j < 4; ++j) {
        float4 w = {ac[0][j], ac[1][j], ac[2][j], ac[3][j]};
        *(float4*)&zts[(tc * 4 + j) * 68 + tn * 4] = w;
    }
#pragma unroll
    for (int i = 0; i < 16; ++i) W_s[tid + i * 256] = wbR[i];
    __syncthreads();                       // bar3: t tile + Wb ready
    // ---- Phase C: h = relu(t @ Wb + bb) ----
    float hc[4][4];
#pragma unroll
    for (int i = 0; i < 4; ++i)
#pragma unroll
        for (int j = 0; j < 4; ++j)
            hc[i][j] = bbv[j];
#pragma unroll 8
    for (int k = 0; k < 64; ++k) {
        float4 tv = *(const float4*)&zts[k * 68 + tn * 4];
        float4 wv = *(const float4*)&W_s[k * 64 + tc * 4];
        const float tf[4] = {tv.x, tv.y, tv.z, tv.w};
        const float wf[4] = {wv.x, wv.y, wv.z, wv.w};
#pragma unroll
        for (int i = 0; i < 4; ++i)
#pragma unroll
            for (int j = 0; j < 4; ++j)
                hc[i][j] = fmaf(tf[i], wf[j], hc[i][j]);
    }
    // ---- epilogue: store bf16 h OR pool directly ----
    if (POOL) {
        int curg = -1; float p0 = 0, p1 = 0, p2 = 0, p3 = 0; int run = 0;
#pragma unroll
        for (int i = 0; i < 4; ++i) {
            int node = blockBase + tn * 4 + i;
            if (node < N) {
                float o0 = fmaxf(hc[i][0], 0.0f), o1 = fmaxf(hc[i][1], 0.0f);
                float o2 = fmaxf(hc[i][2], 0.0f), o3 = fmaxf(hc[i][3], 0.0f);
                sv[0] += o0; sv[1] += o1; sv[2] += o2; sv[3] += o3;
                qv[0] += o0 * o0; qv[1] += o1 * o1; qv[2] += o2 * o2; qv[3] += o3 * o3;
                int gid = batch[node];
                if (gid != curg) {
                    if (curg >= 0) {
                        unsafeAtomicAdd(&pool[(size_t)curg * 64 + tc * 4 + 0], p0);
                        unsafeAtomicAdd(&pool[(size_t)curg * 64 + tc * 4 + 1], p1);
                        unsafeAtomicAdd(&pool[(size_t)curg * 64 + tc * 4 + 2], p2);
                        unsafeAtomicAdd(&pool[(size_t)curg * 64 + tc * 4 + 3], p3);
                        if (tc == 0) unsafeAtomicAdd(&cnt[curg], (float)run);
                    }
                    curg = gid; p0 = p1 = p2 = p3 = 0.0f; run = 0;
                }
                p0 += o0; p1 += o1; p2 += o2; p3 += o3; run++;
            }
        }
        if (curg >= 0) {
            unsafeAtomicAdd(&pool[(size_t)curg * 64 + tc * 4 + 0], p0);
            unsafeAtomicAdd(&pool[(size_t)curg * 64 + tc * 4 + 1], p1);
            unsafeAtomicAdd(&pool[(size_t)curg * 64 + tc * 4 + 2], p2);
            unsafeAtomicAdd(&pool[(size_t)curg * 64 + tc * 4 + 3], p3);
            if (tc == 0) unsafeAtomicAdd(&cnt[curg], (float)run);
        }
    } else {
#pragma unroll
        for (int i = 0; i < 4; ++i) {
            int node = blockBase + tn * 4 + i;
            if (node < N) {
                float o0 = fmaxf(hc[i][0], 0.0f), o1 = fmaxf(hc[i][1], 0.0f);
                float o2 = fmaxf(hc[i][2], 0.0f), o3 = fmaxf(hc[i][3], 0.0f);
                ushort4 ob = {f2bf(o0), f2bf(o1), f2bf(o2), f2bf(o3)};
                *(ushort4*)&hout[(size_t)node * 64 + tc * 4] = ob;
                sv[0] += o0; sv[1] += o1; sv[2] += o2; sv[3] += o3;
                qv[0] += o0 * o0; qv[1] += o1 * o1; qv[2] += o2 * o2; qv[3] += o3 * o3;
            }
        }
    }
    // ---- stats: wave reduce -> block LDS -> replicated global slot ----
#pragma unroll
    for (int off = 16; off < 64; off <<= 1) {
#pragma unroll
        for (int j = 0; j < 4; ++j) {
            sv[j] += __shfl_xor(sv[j], off);
            qv[j] += __shfl_xor(qv[j], off);
        }
    }
    if ((tid & 63) < 16) {
#pragma unroll
        for (int j = 0; j < 4; ++j) {
            atomicAdd(&statS[tc * 4 + j], sv[j]);
            atomicAdd(&statS[64 + tc * 4 + j], qv[j]);
        }
    }
    __syncthreads();
    if (tid < 128) unsafeAtomicAdd(&stats[(blockIdx.x & (SREP - 1)) * 128 + tid], statS[tid]);
}

// ================= readout (applies BN3 affine to pooled mean) =================
__global__ void readout_kernel(const float* __restrict__ pool, const float* __restrict__ cnt,
                               const float* __restrict__ stats, const float* __restrict__ g3,
                               const float* __restrict__ be3,
                               const float* __restrict__ Wf1, const float* __restrict__ bf1,
                               const float* __restrict__ Wf2, const float* __restrict__ bf2,
                               float* __restrict__ out, int N) {
    int gb = blockIdx.x;
    int t = threadIdx.x;  // 64 threads
    float invN = 1.0f / (float)N;
    float s0 = 0, s1 = 0;
#pragma unroll
    for (int r = 0; r < SREP; ++r) {
        s0 += stats[r * 128 + t];
        s1 += stats[r * 128 + 64 + t];
    }
    float mu = s0 * invN;
    float var = s1 * invN - mu * mu;
    float inv = rsqrtf(var + 1e-5f);
    float a = g3[t] * inv;
    float c = be3[t] - mu * a;
    float cn = cnt[gb];
    float p = (cn > 0.0f) ? (a * (pool[(size_t)gb * 64 + t] / cn) + c) : 0.0f;
    float o = 0.0f;
#pragma unroll
    for (int j = 0; j < 10; j++) {
        float part = p * Wf1[t * 10 + j];
#pragma unroll
        for (int off = 32; off > 0; off >>= 1) part += __shfl_down(part, off);
        float z = fmaxf(part + bf1[j], 0.0f);   // valid on lane 0 only
        o = fmaf(z, Wf2[j], o);
    }
    if (t == 0) out[gb] = o + bf2[0];
}

extern "C" void kernel_launch(void* const* d_in, const int* in_sizes, int n_in,
                              void* d_out, int out_size, void* d_ws, size_t ws_size,
                              hipStream_t stream) {
    const float* x      = (const float*)d_in[0];
    const int*   ei     = (const int*)d_in[1];
    const int*   batch  = (const int*)d_in[2];
    const float* W1a = (const float*)d_in[3];  const float* b1a = (const float*)d_in[4];
    const float* W1b = (const float*)d_in[5];  const float* b1b = (const float*)d_in[6];
    const float* e1  = (const float*)d_in[7];  const float* g1  = (const float*)d_in[8];
    const float* be1 = (const float*)d_in[9];
    const float* W2a = (const float*)d_in[10]; const float* b2a = (const float*)d_in[11];
    const float* W2b = (const float*)d_in[12]; const float* b2b = (const float*)d_in[13];
    const float* e2  = (const float*)d_in[14]; const float* g2  = (const float*)d_in[15];
    const float* be2 = (const float*)d_in[16];
    const float* W3a = (const float*)d_in[17]; const float* b3a = (const float*)d_in[18];
    const float* W3b = (const float*)d_in[19]; const float* b3b = (const float*)d_in[20];
    const float* e3  = (const float*)d_in[21]; const float* g3  = (const float*)d_in[22];
    const float* be3 = (const float*)d_in[23];
    const float* Wf1 = (const float*)d_in[24]; const float* bf1 = (const float*)d_in[25];
    const float* Wf2 = (const float*)d_in[26]; const float* bf2 = (const float*)d_in[27];

    const int N = in_sizes[2];
    const int E = in_sizes[1] / 2;
    const int G = out_size;
    const int NBUCK = (N + 511) >> BSH;
    const int C = (E + NBLK - 1) / NBLK;

    // ---------- workspace layout ----------
    int* csr       = (int*)d_ws;               // E
    int* row_start = csr + E;                  // N+64
    int* bpack     = row_start + N + 64;       // E
    int* ghist     = bpack + E;                // NBLK*256
    int* total     = ghist + NBLK * 256;       // 256
    int* bbase     = total + 256;              // 272
    // --- contiguous zero-init region ---
    float* stats   = (float*)(bbase + 272);    // 3 * SREP*128
    float* pool    = stats + 3 * SREP * 128;   // G*64
    float* cnt     = pool + (size_t)G * HD;    // G
    // --- end zero region ---
    float* aggr    = cnt + G;                  // N*64 f32
    size_t NH = (size_t)N * HD;
    u16* hA        = (u16*)(aggr + NH);        // N*64 bf16
    u16* hB        = hA + NH;                  // N*64 bf16

    const int TB = 256;
    int fusedGrid = (N + 63) / 64;
    size_t zeroBytes = (size_t)(3 * SREP * 128 + (size_t)G * HD + G) * sizeof(float);

    // ---------- CSR build (deterministic two-pass bucket sort) ----------
    hipMemsetAsync(stats, 0, zeroBytes, stream);
    hist_kernel<<<NBLK, 256, 0, stream>>>(ei, ghist, E, C);
    colscan_kernel<<<NBUCK, 256, 0, stream>>>(ghist, total);
    base_kernel<<<1, 256, 0, stream>>>(total, bbase, NBUCK);
    scatter_kernel<<<NBLK, 256, 0, stream>>>(ei, ghist, bbase, bpack, E, C);
    csrbuild_kernel<<<NBUCK, 256, 0, stream>>>(bpack, bbase, row_start, csr, N);

    // ---------- layer 1: x(16,f32) -> hA(bf16), stats1 ----------
    gather16_kernel<<<((N + 15) / 16 * 64 + TB - 1) / TB, TB, 0, stream>>>(x, row_start, csr, aggr, N);
    fused_mlp_kernel<16, false, false><<<fusedGrid, TB, 0, stream>>>(
        x, aggr, row_start, batch, W1a, b1a, W1b, b1b, e1,
        nullptr, nullptr, nullptr, hA, stats, nullptr, nullptr, N);

    // ---------- layer 2: hA(bf16) -> hB(bf16), BN1 folded ----------
    gather64_kernel<<<((N + 3) / 4 * 64 + TB - 1) / TB, TB, 0, stream>>>(hA, row_start, csr, aggr, N);
    fused_mlp_kernel<64, true, false><<<fusedGrid, TB, 0, stream>>>(
        hA, aggr, row_start, batch, W2a, b2a, W2b, b2b, e2,
        stats, g1, be1, hB, stats + SREP * 128, nullptr, nullptr, N);

    // ---------- layer 3: hB(bf16) -> pooled directly (POOL), BN2 folded ----------
    gather64_kernel<<<((N + 3) / 4 * 64 + TB - 1) / TB, TB, 0, stream>>>(hB, row_start, csr, aggr, N);
    fused_mlp_kernel<64, true, true><<<fusedGrid, TB, 0, stream>>>(
        hB, aggr, row_start, batch, W3a, b3a, W3b, b3b, e3,
        stats + SREP * 128, g2, be2, hA /*unused*/, stats + 2 * SREP * 128, pool, cnt, N);

    // ---------- readout (BN3 affine on pooled mean) ----------
    readout_kernel<<<G, 64, 0, stream>>>(pool, cnt, stats + 2 * SREP * 128, g3, be3,
                                         Wf1, bf1, Wf2, bf2, (float*)d_out, N);
}

// Round 14
// 371.054 us; speedup vs baseline: 1.1917x; 1.0329x over previous
//
#include <hip/hip_runtime.h>
#include <hip/hip_bf16.h>

// GIN net, round 14. r13 counters: POOL layer WRITE_SIZE 27.3MB (~payload 1MB)
// = 400k pool atomics bouncing 64B lines across the 8 non-coherent XCD L2s.
// Fix 1: pool/cnt replicated x8, replica = blockIdx&7 (approx-XCD partition;
// same trick as stats SREP). Fix 2: grid-stride persistent MLP (grid=1024 =
// 4 blocks/CU exactly); BOTH Wa and Wb live in registers, written into the
// single time-shared W_s per tile -> weight GLOBAL loads once per block, not
// per tile; cross-tile feature prefetch. Numerics identical to r13/r11.

#define HD 64
#define NBLK 256
#define BSH 9        // bucket = 512 nodes; requires N <= 131072
#define SREP 8       // stats + pool replication

typedef unsigned short u16;
typedef unsigned int u32;

__device__ __forceinline__ float bf2f(u16 u) {
    return __uint_as_float(((u32)u) << 16);
}
__device__ __forceinline__ u16 f2bf(float f) {       // round-to-nearest-even
    u32 u = __float_as_uint(f);
    u32 r = 0x7FFFu + ((u >> 16) & 1u);
    return (u16)((u + r) >> 16);
}

// ================= CSR build: deterministic two-pass bucket sort =================
__global__ void hist_kernel(const int* __restrict__ ei, int* __restrict__ ghist, int E, int C) {
    __shared__ int lh[256];
    int b = blockIdx.x, tid = threadIdx.x;
    lh[tid] = 0;
    __syncthreads();
    int beg = b * C, end = min(beg + C, E);
    for (int i = beg + tid; i < end; i += 256) atomicAdd(&lh[ei[E + i] >> BSH], 1);
    __syncthreads();
    ghist[b * 256 + tid] = lh[tid];
}

__global__ void colscan_kernel(int* __restrict__ ghist, int* __restrict__ total) {
    __shared__ int s[256];
    int k = blockIdx.x, b = threadIdx.x;
    int v = ghist[b * 256 + k];
    s[b] = v;
    __syncthreads();
    for (int off = 1; off < 256; off <<= 1) {
        int u = (b >= off) ? s[b - off] : 0;
        __syncthreads();
        s[b] += u;
        __syncthreads();
    }
    ghist[b * 256 + k] = s[b] - v;
    if (b == 255) total[k] = s[255];
}

__global__ void base_kernel(const int* __restrict__ total, int* __restrict__ bbase, int NBUCK) {
    __shared__ int s[256];
    int t = threadIdx.x;
    int v = (t < NBUCK) ? total[t] : 0;
    s[t] = v;
    __syncthreads();
    for (int off = 1; off < 256; off <<= 1) {
        int u = (t >= off) ? s[t - off] : 0;
        __syncthreads();
        s[t] += u;
        __syncthreads();
    }
    if (t == 0) bbase[0] = 0;
    bbase[t + 1] = s[t];
}

__global__ void scatter_kernel(const int* __restrict__ ei, const int* __restrict__ ghist,
                               const int* __restrict__ bbase, int* __restrict__ bpack,
                               int E, int C) {
    __shared__ int lcur[256];
    int b = blockIdx.x, tid = threadIdx.x;
    lcur[tid] = bbase[tid] + ghist[b * 256 + tid];
    __syncthreads();
    int beg = b * C, end = min(beg + C, E);
    for (int i = beg + tid; i < end; i += 256) {
        int src = ei[i], dst = ei[E + i];
        int pos = atomicAdd(&lcur[dst >> BSH], 1);
        bpack[pos] = src | ((dst & 511) << 17);
    }
}

__global__ void csrbuild_kernel(const int* __restrict__ bpack, const int* __restrict__ bbase,
                                int* __restrict__ row_start, int* __restrict__ csr, int N) {
    __shared__ int h[512], s[512], lc[512];
    int k = blockIdx.x, tid = threadIdx.x;
    int beg = bbase[k], end = bbase[k + 1];
    h[tid] = 0; h[tid + 256] = 0;
    __syncthreads();
    for (int i = beg + tid; i < end; i += 256) atomicAdd(&h[(bpack[i] >> 17) & 511], 1);
    __syncthreads();
    s[tid] = h[tid]; s[tid + 256] = h[tid + 256];
    __syncthreads();
    for (int off = 1; off < 512; off <<= 1) {
        int v0 = (tid >= off) ? s[tid - off] : 0;
        int t1 = tid + 256;
        int v1 = (t1 >= off) ? s[t1 - off] : 0;
        __syncthreads();
        s[tid] += v0; s[t1] += v1;
        __syncthreads();
    }
    int e0 = s[tid] - h[tid], e1 = s[tid + 256] - h[tid + 256];
    lc[tid] = e0; lc[tid + 256] = e1;
    int n0 = (k << BSH) + tid, n1 = (k << BSH) + tid + 256;
    if (n0 < N) row_start[n0] = beg + e0;
    if (n1 < N) row_start[n1] = beg + e1;
    if (k == gridDim.x - 1 && tid == 0) row_start[N] = end;
    __syncthreads();
    for (int i = beg + tid; i < end; i += 256) {
        int v = bpack[i];
        int pos = beg + atomicAdd(&lc[(v >> 17) & 511], 1);
        csr[pos] = v & 0x1FFFF;
    }
}

// ======== gather64: bf16 rows in, f32 aggr out; 16 lanes/node, 4-wide ILP ========
__global__ void gather64_kernel(const u16* __restrict__ x, const int* __restrict__ rs,
                                const int* __restrict__ csr, float* __restrict__ aggr, int N) {
    int lane = threadIdx.x & 63;
    int l4 = lane & 15;
    int wave = (blockIdx.x * blockDim.x + threadIdx.x) >> 6;
    int n = wave * 4 + (lane >> 4);
    if (n >= N) return;
    int beg = rs[n], end = rs[n + 1];
    const u16* xb = x + (size_t)l4 * 4;
    float a0x = 0, a0y = 0, a0z = 0, a0w = 0;
    float a1x = 0, a1y = 0, a1z = 0, a1w = 0;
    float a2x = 0, a2y = 0, a2z = 0, a2w = 0;
    float a3x = 0, a3y = 0, a3z = 0, a3w = 0;
    for (int base = beg; base < end; base += 16) {
        int cnt = end - base; if (cnt > 16) cnt = 16;
        int e = (l4 < cnt) ? csr[base + l4] : 0;
        int j = 0;
        for (; j + 4 <= cnt; j += 4) {
            int s0 = __shfl(e, j + 0, 16);
            int s1 = __shfl(e, j + 1, 16);
            int s2 = __shfl(e, j + 2, 16);
            int s3 = __shfl(e, j + 3, 16);
            ushort4 u0 = *(const ushort4*)(xb + (size_t)s0 * 64);
            ushort4 u1 = *(const ushort4*)(xb + (size_t)s1 * 64);
            ushort4 u2 = *(const ushort4*)(xb + (size_t)s2 * 64);
            ushort4 u3 = *(const ushort4*)(xb + (size_t)s3 * 64);
            a0x += bf2f(u0.x); a0y += bf2f(u0.y); a0z += bf2f(u0.z); a0w += bf2f(u0.w);
            a1x += bf2f(u1.x); a1y += bf2f(u1.y); a1z += bf2f(u1.z); a1w += bf2f(u1.w);
            a2x += bf2f(u2.x); a2y += bf2f(u2.y); a2z += bf2f(u2.z); a2w += bf2f(u2.w);
            a3x += bf2f(u3.x); a3y += bf2f(u3.y); a3z += bf2f(u3.z); a3w += bf2f(u3.w);
        }
        for (; j < cnt; j++) {
            int s = __shfl(e, j, 16);
            ushort4 u = *(const ushort4*)(xb + (size_t)s * 64);
            a0x += bf2f(u.x); a0y += bf2f(u.y); a0z += bf2f(u.z); a0w += bf2f(u.w);
        }
    }
    float4 o;
    o.x = (a0x + a1x) + (a2x + a3x);
    o.y = (a0y + a1y) + (a2y + a3y);
    o.z = (a0z + a1z) + (a2z + a3z);
    o.w = (a0w + a1w) + (a2w + a3w);
    *reinterpret_cast<float4*>(aggr + (size_t)n * 64 + l4 * 4) = o;
}

// gather16: layer-1 input x is f32; aggr stays f32
__global__ void gather16_kernel(const float* __restrict__ x, const int* __restrict__ rs,
                                const int* __restrict__ csr, float* __restrict__ aggr, int N) {
    int lane = threadIdx.x & 63;
    int l4 = lane & 3;
    int wave = (blockIdx.x * blockDim.x + threadIdx.x) >> 6;
    int n = wave * 16 + (lane >> 2);
    if (n >= N) return;
    int beg = rs[n], end = rs[n + 1];
    const float* xb = x + (size_t)l4 * 4;
    float a0x = 0, a0y = 0, a0z = 0, a0w = 0;
    float a1x = 0, a1y = 0, a1z = 0, a1w = 0;
    float a2x = 0, a2y = 0, a2z = 0, a2w = 0;
    float a3x = 0, a3y = 0, a3z = 0, a3w = 0;
    for (int base = beg; base < end; base += 4) {
        int cnt = end - base; if (cnt > 4) cnt = 4;
        int e = (l4 < cnt) ? csr[base + l4] : 0;
        if (cnt == 4) {
            int s0 = __shfl(e, 0, 4);
            int s1 = __shfl(e, 1, 4);
            int s2 = __shfl(e, 2, 4);
            int s3 = __shfl(e, 3, 4);
            float4 v0 = *(const float4*)(xb + (size_t)s0 * 16);
            float4 v1 = *(const float4*)(xb + (size_t)s1 * 16);
            float4 v2 = *(const float4*)(xb + (size_t)s2 * 16);
            float4 v3 = *(const float4*)(xb + (size_t)s3 * 16);
            a0x += v0.x; a0y += v0.y; a0z += v0.z; a0w += v0.w;
            a1x += v1.x; a1y += v1.y; a1z += v1.z; a1w += v1.w;
            a2x += v2.x; a2y += v2.y; a2z += v2.z; a2w += v2.w;
            a3x += v3.x; a3y += v3.y; a3z += v3.z; a3w += v3.w;
        } else {
            for (int j = 0; j < cnt; j++) {
                int s = __shfl(e, j, 4);
                float4 v = *(const float4*)(xb + (size_t)s * 16);
                a0x += v.x; a0y += v.y; a0z += v.z; a0w += v.w;
            }
        }
    }
    float4 o;
    o.x = (a0x + a1x) + (a2x + a3x);
    o.y = (a0y + a1y) + (a2y + a3y);
    o.z = (a0z + a1z) + (a2z + a3z);
    o.w = (a0w + a1w) + (a2w + a3w);
    *reinterpret_cast<float4*>(aggr + (size_t)n * 16 + l4 * 4) = o;
}

// ======== fused MLP: grid-stride persistent, weights in registers, one W_s ========
template <int DIN, bool AFF, bool POOL>
__launch_bounds__(256)
__global__ void fused_mlp_kernel(const void* __restrict__ xin_, const float* __restrict__ aggr,
                                 const int* __restrict__ rs, const int* __restrict__ batch,
                                 const float* __restrict__ Wa, const float* __restrict__ ba,
                                 const float* __restrict__ Wb, const float* __restrict__ bb,
                                 const float* __restrict__ epsp,
                                 const float* __restrict__ statsPrev,
                                 const float* __restrict__ gPrev, const float* __restrict__ bePrev,
                                 u16* __restrict__ hout, float* __restrict__ stats,
                                 float* __restrict__ pool, float* __restrict__ cnt,
                                 int N, int G) {
    __shared__ float W_s[64 * 64];     // time-shared: Wa (Phase B) then Wb (Phase C)
    __shared__ float zts[64 * 68];
    __shared__ float statS[128];
    __shared__ float degS[64];
    __shared__ float aS[64], cS[64], uS[64];

    const int tid = threadIdx.x;
    const int tc = tid & 15;
    const int tn = tid >> 4;
    const float* xinF = (const float*)xin_;
    const u16*   xinB = (const u16*)xin_;
    constexpr int WAn = DIN / 4;       // waR register count

    const int ntiles = (N + 63) >> 6;
    const int rep = blockIdx.x & (SREP - 1);
    float* poolR = POOL ? pool + (size_t)rep * G * 64 : nullptr;
    float* cntR  = POOL ? cnt + (size_t)rep * G : nullptr;

    // ---- prefetch tile-0 features (longest latency first) ----
    int tile = blockIdx.x;
    ushort4 xuP[4]; float4 avP[4];     // DIN==64
    float4  xvP, av16P;                // DIN==16
    {
        int blockBase = tile * 64;
        if (DIN == 64) {
#pragma unroll
            for (int i = 0; i < 4; ++i) {
                int node = blockBase + tn * 4 + i;
                xuP[i] = make_ushort4(0, 0, 0, 0);
                avP[i] = make_float4(0, 0, 0, 0);
                if (node < N) {
                    xuP[i] = *(const ushort4*)&xinB[(size_t)node * 64 + tc * 4];
                    avP[i] = *(const float4*)&aggr[(size_t)node * 64 + tc * 4];
                }
            }
        } else {
            int node = blockBase + tn * 4 + (tc >> 2);
            xvP = make_float4(0, 0, 0, 0);
            av16P = make_float4(0, 0, 0, 0);
            if (node < N) {
                xvP = *(const float4*)&xinF[(size_t)node * 16 + (tc & 3) * 4];
                av16P = *(const float4*)&aggr[(size_t)node * 16 + (tc & 3) * 4];
            }
        }
    }
    // ---- Wb into registers ----
    float wbR[16];
#pragma unroll
    for (int i = 0; i < 16; ++i) wbR[i] = Wb[tid + i * 256];

    // ---- Wa into registers (AFF: BN-folded) ----
    float waR[WAn];
    if (AFF) {
        if (tid < 64) {
            float invN = 1.0f / (float)N;
            float s0 = 0, s1 = 0;
#pragma unroll
            for (int r = 0; r < SREP; ++r) {
                s0 += statsPrev[r * 128 + tid];
                s1 += statsPrev[r * 128 + 64 + tid];
            }
            float mu = s0 * invN;
            float var = s1 * invN - mu * mu;
            float inv = rsqrtf(var + 1e-5f);
            float a = gPrev[tid] * inv;
            aS[tid] = a;
            cS[tid] = bePrev[tid] - mu * a;
        }
        __syncthreads();
#pragma unroll
        for (int i = 0; i < WAn; ++i) {
            int idx = tid + i * 256;
            waR[i] = aS[idx >> 6] * Wa[idx];
        }
        if (tid < 64) {
            float s = 0.0f;
            for (int k = 0; k < 64; k++) s = fmaf(cS[k], Wa[k * 64 + tid], s);
            uS[tid] = s;
        }
    } else {
#pragma unroll
        for (int i = 0; i < WAn; ++i) waR[i] = Wa[tid + i * 256];
    }
    if (tid < 128) statS[tid] = 0.0f;
    const float e1 = 1.0f + epsp[0];

    float4 t4;
    t4 = *(const float4*)&ba[tc * 4];
    const float bav[4] = {t4.x, t4.y, t4.z, t4.w};
    t4 = *(const float4*)&bb[tc * 4];
    const float bbv[4] = {t4.x, t4.y, t4.z, t4.w};

    float sv[4] = {0, 0, 0, 0}, qv[4] = {0, 0, 0, 0};
    float uv[4] = {0, 0, 0, 0};
    bool uvLoaded = false;

    // ================= grid-stride tile loop =================
    for (; tile < ntiles; tile += gridDim.x) {
        int blockBase = tile * 64;
        __syncthreads();                   // bar_pre: prev tile's LDS reads done (also covers prologue)
        // ---- write Wa + z tile + degS into LDS ----
#pragma unroll
        for (int i = 0; i < WAn; ++i) W_s[tid + i * 256] = waR[i];
        float zr[4][4];
        if (DIN == 64) {
#pragma unroll
            for (int i = 0; i < 4; ++i) {
                zr[i][0] = fmaf(e1, bf2f(xuP[i].x), avP[i].x);
                zr[i][1] = fmaf(e1, bf2f(xuP[i].y), avP[i].y);
                zr[i][2] = fmaf(e1, bf2f(xuP[i].z), avP[i].z);
                zr[i][3] = fmaf(e1, bf2f(xuP[i].w), avP[i].w);
            }
#pragma unroll
            for (int j = 0; j < 4; ++j) {
                float4 w = {zr[0][j], zr[1][j], zr[2][j], zr[3][j]};
                *(float4*)&zts[(tc * 4 + j) * 68 + tn * 4] = w;
            }
        } else {
            zr[0][0] = fmaf(e1, xvP.x, av16P.x);
            zr[0][1] = fmaf(e1, xvP.y, av16P.y);
            zr[0][2] = fmaf(e1, xvP.z, av16P.z);
            zr[0][3] = fmaf(e1, xvP.w, av16P.w);
#pragma unroll
            for (int j = 0; j < 4; ++j)
                zts[((tc & 3) * 4 + j) * 68 + tn * 4 + (tc >> 2)] = zr[0][j];
        }
        if (AFF && tid < 64) {
            int node = blockBase + tid;
            degS[tid] = (node < N) ? (float)(rs[node + 1] - rs[node]) : 0.0f;
        }
        // ---- prefetch next tile's features ----
        {
            int nt = tile + gridDim.x;
            if (nt < ntiles) {
                int nb = nt * 64;
                if (DIN == 64) {
#pragma unroll
                    for (int i = 0; i < 4; ++i) {
                        int node = nb + tn * 4 + i;
                        ushort4 xu = make_ushort4(0, 0, 0, 0);
                        float4 av = make_float4(0, 0, 0, 0);
                        if (node < N) {
                            xu = *(const ushort4*)&xinB[(size_t)node * 64 + tc * 4];
                            av = *(const float4*)&aggr[(size_t)node * 64 + tc * 4];
                        }
                        xuP[i] = xu; avP[i] = av;
                    }
                } else {
                    int node = nb + tn * 4 + (tc >> 2);
                    float4 xv = make_float4(0, 0, 0, 0), av = make_float4(0, 0, 0, 0);
                    if (node < N) {
                        xv = *(const float4*)&xinF[(size_t)node * 16 + (tc & 3) * 4];
                        av = *(const float4*)&aggr[(size_t)node * 16 + (tc & 3) * 4];
                    }
                    xvP = xv; av16P = av;
                }
            }
        }
        __syncthreads();                   // bar1: W_s(Wa) + z tile + degS ready
        if (AFF && !uvLoaded) {
            uv[0] = uS[tc * 4]; uv[1] = uS[tc * 4 + 1];
            uv[2] = uS[tc * 4 + 2]; uv[3] = uS[tc * 4 + 3];
            uvLoaded = true;
        }
        float dg[4];
        if (AFF) {
#pragma unroll
            for (int i = 0; i < 4; ++i) dg[i] = e1 + degS[tn * 4 + i];
        }
        // ---- Phase B: t = relu(z @ Wa + bias) ----
        float ac[4][4];
#pragma unroll
        for (int i = 0; i < 4; ++i)
#pragma unroll
            for (int j = 0; j < 4; ++j)
                ac[i][j] = AFF ? fmaf(dg[i], uv[j], bav[j]) : bav[j];
#pragma unroll 8
        for (int k = 0; k < DIN; ++k) {
            float4 zv = *(const float4*)&zts[k * 68 + tn * 4];
            float4 wv = *(const float4*)&W_s[k * 64 + tc * 4];
            const float zf[4] = {zv.x, zv.y, zv.z, zv.w};
            const float wf[4] = {wv.x, wv.y, wv.z, wv.w};
#pragma unroll
            for (int i = 0; i < 4; ++i)
#pragma unroll
                for (int j = 0; j < 4; ++j)
                    ac[i][j] = fmaf(zf[i], wf[j], ac[i][j]);
        }
#pragma unroll
        for (int i = 0; i < 4; ++i)
#pragma unroll
            for (int j = 0; j < 4; ++j)
                ac[i][j] = fmaxf(ac[i][j], 0.0f);
        __syncthreads();                   // bar2: z tile + Wa consumed
        // ---- write t tile AND Wb into LDS ----
#pragma unroll
        for (int j = 0; j < 4; ++j) {
            float4 w = {ac[0][j], ac[1][j], ac[2][j], ac[3][j]};
            *(float4*)&zts[(tc * 4 + j) * 68 + tn * 4] = w;
        }
#pragma unroll
        for (int i = 0; i < 16; ++i) W_s[tid + i * 256] = wbR[i];
        __syncthreads();                   // bar3: t tile + Wb ready
        // ---- Phase C: h = relu(t @ Wb + bb) ----
        float hc[4][4];
#pragma unroll
        for (int i = 0; i < 4; ++i)
#pragma unroll
            for (int j = 0; j < 4; ++j)
                hc[i][j] = bbv[j];
#pragma unroll 8
        for (int k = 0; k < 64; ++k) {
            float4 tv = *(const float4*)&zts[k * 68 + tn * 4];
            float4 wv = *(const float4*)&W_s[k * 64 + tc * 4];
            const float tf[4] = {tv.x, tv.y, tv.z, tv.w};
            const float wf[4] = {wv.x, wv.y, wv.z, wv.w};
#pragma unroll
            for (int i = 0; i < 4; ++i)
#pragma unroll
                for (int j = 0; j < 4; ++j)
                    hc[i][j] = fmaf(tf[i], wf[j], hc[i][j]);
        }
        // ---- epilogue: store bf16 h OR pool into XCD-local replica ----
        if (POOL) {
            int curg = -1; float p0 = 0, p1 = 0, p2 = 0, p3 = 0; int run = 0;
#pragma unroll
            for (int i = 0; i < 4; ++i) {
                int node = blockBase + tn * 4 + i;
                if (node < N) {
                    float o0 = fmaxf(hc[i][0], 0.0f), o1 = fmaxf(hc[i][1], 0.0f);
                    float o2 = fmaxf(hc[i][2], 0.0f), o3 = fmaxf(hc[i][3], 0.0f);
                    sv[0] += o0; sv[1] += o1; sv[2] += o2; sv[3] += o3;
                    qv[0] += o0 * o0; qv[1] += o1 * o1; qv[2] += o2 * o2; qv[3] += o3 * o3;
                    int gid = batch[node];
                    if (gid != curg) {
                        if (curg >= 0) {
                            unsafeAtomicAdd(&poolR[(size_t)curg * 64 + tc * 4 + 0], p0);
                            unsafeAtomicAdd(&poolR[(size_t)curg * 64 + tc * 4 + 1], p1);
                            unsafeAtomicAdd(&poolR[(size_t)curg * 64 + tc * 4 + 2], p2);
                            unsafeAtomicAdd(&poolR[(size_t)curg * 64 + tc * 4 + 3], p3);
                            if (tc == 0) unsafeAtomicAdd(&cntR[curg], (float)run);
                        }
                        curg = gid; p0 = p1 = p2 = p3 = 0.0f; run = 0;
                    }
                    p0 += o0; p1 += o1; p2 += o2; p3 += o3; run++;
                }
            }
            if (curg >= 0) {
                unsafeAtomicAdd(&poolR[(size_t)curg * 64 + tc * 4 + 0], p0);
                unsafeAtomicAdd(&poolR[(size_t)curg * 64 + tc * 4 + 1], p1);
                unsafeAtomicAdd(&poolR[(size_t)curg * 64 + tc * 4 + 2], p2);
                unsafeAtomicAdd(&poolR[(size_t)curg * 64 + tc * 4 + 3], p3);
                if (tc == 0) unsafeAtomicAdd(&cntR[curg], (float)run);
            }
        } else {
#pragma unroll
            for (int i = 0; i < 4; ++i) {
                int node = blockBase + tn * 4 + i;
                if (node < N) {
                    float o0 = fmaxf(hc[i][0], 0.0f), o1 = fmaxf(hc[i][1], 0.0f);
                    float o2 = fmaxf(hc[i][2], 0.0f), o3 = fmaxf(hc[i][3], 0.0f);
                    ushort4 ob = {f2bf(o0), f2bf(o1), f2bf(o2), f2bf(o3)};
                    *(ushort4*)&hout[(size_t)node * 64 + tc * 4] = ob;
                    sv[0] += o0; sv[1] += o1; sv[2] += o2; sv[3] += o3;
                    qv[0] += o0 * o0; qv[1] += o1 * o1; qv[2] += o2 * o2; qv[3] += o3 * o3;
                }
            }
        }
    }
    // ---- stats: wave reduce -> block LDS -> replicated global slot ----
#pragma unroll
    for (int off = 16; off < 64; off <<= 1) {
#pragma unroll
        for (int j = 0; j < 4; ++j) {
            sv[j] += __shfl_xor(sv[j], off);
            qv[j] += __shfl_xor(qv[j], off);
        }
    }
    if ((tid & 63) < 16) {
#pragma unroll
        for (int j = 0; j < 4; ++j) {
            atomicAdd(&statS[tc * 4 + j], sv[j]);
            atomicAdd(&statS[64 + tc * 4 + j], qv[j]);
        }
    }
    __syncthreads();
    if (tid < 128) unsafeAtomicAdd(&stats[rep * 128 + tid], statS[tid]);
}

// ================= readout (sums 8 pool replicas; BN3 affine on mean) ==========
__global__ void readout_kernel(const float* __restrict__ pool, const float* __restrict__ cnt,
                               const float* __restrict__ stats, const float* __restrict__ g3,
                               const float* __restrict__ be3,
                               const float* __restrict__ Wf1, const float* __restrict__ bf1,
                               const float* __restrict__ Wf2, const float* __restrict__ bf2,
                               float* __restrict__ out, int N, int G) {
    int gb = blockIdx.x;
    int t = threadIdx.x;  // 64 threads
    float invN = 1.0f / (float)N;
    float s0 = 0, s1 = 0, ps = 0, cs = 0;
#pragma unroll
    for (int r = 0; r < SREP; ++r) {
        s0 += stats[r * 128 + t];
        s1 += stats[r * 128 + 64 + t];
        ps += pool[(size_t)r * G * 64 + (size_t)gb * 64 + t];
        cs += cnt[(size_t)r * G + gb];
    }
    float mu = s0 * invN;
    float var = s1 * invN - mu * mu;
    float inv = rsqrtf(var + 1e-5f);
    float a = g3[t] * inv;
    float c = be3[t] - mu * a;
    float p = (cs > 0.0f) ? (a * (ps / cs) + c) : 0.0f;
    float o = 0.0f;
#pragma unroll
    for (int j = 0; j < 10; j++) {
        float part = p * Wf1[t * 10 + j];
#pragma unroll
        for (int off = 32; off > 0; off >>= 1) part += __shfl_down(part, off);
        float z = fmaxf(part + bf1[j], 0.0f);   // valid on lane 0 only
        o = fmaf(z, Wf2[j], o);
    }
    if (t == 0) out[gb] = o + bf2[0];
}

extern "C" void kernel_launch(void* const* d_in, const int* in_sizes, int n_in,
                              void* d_out, int out_size, void* d_ws, size_t ws_size,
                              hipStream_t stream) {
    const float* x      = (const float*)d_in[0];
    const int*   ei     = (const int*)d_in[1];
    const int*   batch  = (const int*)d_in[2];
    const float* W1a = (const float*)d_in[3];  const float* b1a = (const float*)d_in[4];
    const float* W1b = (const float*)d_in[5];  const float* b1b = (const float*)d_in[6];
    const float* e1  = (const float*)d_in[7];  const float* g1  = (const float*)d_in[8];
    const float* be1 = (const float*)d_in[9];
    const float* W2a = (const float*)d_in[10]; const float* b2a = (const float*)d_in[11];
    const float* W2b = (const float*)d_in[12]; const float* b2b = (const float*)d_in[13];
    const float* e2  = (const float*)d_in[14]; const float* g2  = (const float*)d_in[15];
    const float* be2 = (const float*)d_in[16];
    const float* W3a = (const float*)d_in[17]; const float* b3a = (const float*)d_in[18];
    const float* W3b = (const float*)d_in[19]; const float* b3b = (const float*)d_in[20];
    const float* e3  = (const float*)d_in[21]; const float* g3  = (const float*)d_in[22];
    const float* be3 = (const float*)d_in[23];
    const float* Wf1 = (const float*)d_in[24]; const float* bf1 = (const float*)d_in[25];
    const float* Wf2 = (const float*)d_in[26]; const float* bf2 = (const float*)d_in[27];

    const int N = in_sizes[2];
    const int E = in_sizes[1] / 2;
    const int G = out_size;
    const int NBUCK = (N + 511) >> BSH;
    const int C = (E + NBLK - 1) / NBLK;
    const int ntiles = (N + 63) / 64;

    // ---------- workspace layout ----------
    int* csr       = (int*)d_ws;               // E
    int* row_start = csr + E;                  // N+64
    int* bpack     = row_start + N + 64;       // E
    int* ghist     = bpack + E;                // NBLK*256
    int* total     = ghist + NBLK * 256;       // 256
    int* bbase     = total + 256;              // 272
    // --- contiguous zero-init region ---
    float* stats   = (float*)(bbase + 272);    // 3 * SREP*128
    float* pool    = stats + 3 * SREP * 128;   // SREP * G * 64
    float* cnt     = pool + (size_t)SREP * G * HD;  // SREP * G
    // --- end zero region ---
    float* aggr    = cnt + (size_t)SREP * G;   // N*64 f32
    size_t NH = (size_t)N * HD;
    u16* hA        = (u16*)(aggr + NH);        // N*64 bf16
    u16* hB        = hA + NH;                  // N*64 bf16

    const int TB = 256;
    int fusedGrid = ntiles < 1024 ? ntiles : 1024;   // 4 blocks/CU exactly
    size_t zeroBytes = ((size_t)3 * SREP * 128 + (size_t)SREP * G * HD + (size_t)SREP * G) * sizeof(float);

    // ---------- CSR build (deterministic two-pass bucket sort) ----------
    hipMemsetAsync(stats, 0, zeroBytes, stream);
    hist_kernel<<<NBLK, 256, 0, stream>>>(ei, ghist, E, C);
    colscan_kernel<<<NBUCK, 256, 0, stream>>>(ghist, total);
    base_kernel<<<1, 256, 0, stream>>>(total, bbase, NBUCK);
    scatter_kernel<<<NBLK, 256, 0, stream>>>(ei, ghist, bbase, bpack, E, C);
    csrbuild_kernel<<<NBUCK, 256, 0, stream>>>(bpack, bbase, row_start, csr, N);

    // ---------- layer 1: x(16,f32) -> hA(bf16), stats1 ----------
    gather16_kernel<<<((N + 15) / 16 * 64 + TB - 1) / TB, TB, 0, stream>>>(x, row_start, csr, aggr, N);
    fused_mlp_kernel<16, false, false><<<fusedGrid, TB, 0, stream>>>(
        x, aggr, row_start, batch, W1a, b1a, W1b, b1b, e1,
        nullptr, nullptr, nullptr, hA, stats, nullptr, nullptr, N, G);

    // ---------- layer 2: hA(bf16) -> hB(bf16), BN1 folded ----------
    gather64_kernel<<<((N + 3) / 4 * 64 + TB - 1) / TB, TB, 0, stream>>>(hA, row_start, csr, aggr, N);
    fused_mlp_kernel<64, true, false><<<fusedGrid, TB, 0, stream>>>(
        hA, aggr, row_start, batch, W2a, b2a, W2b, b2b, e2,
        stats, g1, be1, hB, stats + SREP * 128, nullptr, nullptr, N, G);

    // ---------- layer 3: hB(bf16) -> pooled directly (POOL), BN2 folded ----------
    gather64_kernel<<<((N + 3) / 4 * 64 + TB - 1) / TB, TB, 0, stream>>>(hB, row_start, csr, aggr, N);
    fused_mlp_kernel<64, true, true><<<fusedGrid, TB, 0, stream>>>(
        hB, aggr, row_start, batch, W3a, b3a, W3b, b3b, e3,
        stats + SREP * 128, g2, be2, hA /*unused*/, stats + 2 * SREP * 128, pool, cnt, N, G);

    // ---------- readout (BN3 affine on pooled mean, sums replicas) ----------
    readout_kernel<<<G, 64, 0, stream>>>(pool, cnt, stats + 2 * SREP * 128, g3, be3,
                                         Wf1, bf1, Wf2, bf2, (float*)d_out, N, G);
}